// Round 6
// baseline (299.615 us; speedup 1.0000x reference)
//
#include <hip/hip_runtime.h>
#include <stdint.h>

#define H_   16
#define NS_  2048
#define B_   4
#define DM_  1024
#define HD_  64
#define MTOT (B_*NS_)   // 8192 tokens

typedef __attribute__((ext_vector_type(8)))  short bf16x8;
typedef __attribute__((ext_vector_type(4)))  float f32x4;
typedef __attribute__((ext_vector_type(16))) float f32x16;

__device__ __forceinline__ unsigned short f2bf(float f){
  union { float f; unsigned u; } v; v.f = f;
  unsigned r = v.u + 0x7FFFu + ((v.u >> 16) & 1u);
  return (unsigned short)(r >> 16);
}
__device__ __forceinline__ float bf2f(unsigned short u){
  union { unsigned u; float f; } v; v.u = ((unsigned)u) << 16;
  return v.f;
}
__device__ __forceinline__ unsigned pk2(float a, float b){
  return (unsigned)f2bf(a) | ((unsigned)f2bf(b) << 16);
}
__device__ __forceinline__ unsigned cvtpk(float a, float b){
  unsigned r;
  asm("v_cvt_pk_bf16_f32 %0, %1, %2" : "=v"(r) : "v"(a), "v"(b));
  return r;
}
__device__ __forceinline__ float exp2a(float x){   // bare v_exp_f32 (2^x)
  float r;
  asm("v_exp_f32 %0, %1" : "=v"(r) : "v"(x));
  return r;
}
__device__ __forceinline__ void gll16(const void* g, void* l){
  __builtin_amdgcn_global_load_lds(
      (const __attribute__((address_space(1))) unsigned int*)g,
      (__attribute__((address_space(3))) unsigned int*)l,
      16, 0, 0);
}

// ---------------- cast hidden_states fp32 -> bf16 ----------------
__global__ void k_cast_x(const float* __restrict__ x, unsigned short* __restrict__ xb){
  long i = ((long)blockIdx.x*256 + threadIdx.x)*4;
  float4 v = *(const float4*)(x + i);
  ushort4 o; o.x=f2bf(v.x); o.y=f2bf(v.y); o.z=f2bf(v.z); o.w=f2bf(v.w);
  *(ushort4*)(xb + i) = o;
}

// ---------------- transpose-cast weight: W[k][n] fp32 -> Wt[n][k] bf16 ----------------
__global__ void k_wt(const float* __restrict__ W, unsigned short* __restrict__ Wt){
  __shared__ float tile[64][65];
  int kt = blockIdx.y*64, nt = blockIdx.x*64;
  int t = threadIdx.x;
  int r = t >> 4, c4 = (t & 15)*4;
#pragma unroll
  for (int i=0;i<4;i++){
    int k = r + i*16;
    float4 v = *(const float4*)(W + (size_t)(kt + k)*DM_ + nt + c4);
    tile[k][c4] = v.x; tile[k][c4+1]=v.y; tile[k][c4+2]=v.z; tile[k][c4+3]=v.w;
  }
  __syncthreads();
#pragma unroll
  for (int i=0;i<4;i++){
    int n = r + i*16;
    ushort4 o;
    o.x = f2bf(tile[c4+0][n]); o.y = f2bf(tile[c4+1][n]);
    o.z = f2bf(tile[c4+2][n]); o.w = f2bf(tile[c4+3][n]);
    *(ushort4*)(Wt + (size_t)(nt + n)*DM_ + kt + c4) = o;
  }
}

// ---------------- RoPE sin/cos table ----------------
__global__ void k_tab(float2* __restrict__ tab){
  int n = blockIdx.x*64 + threadIdx.x;
  int f = n >> 8, rem = n & 255, hh = rem >> 4, ww = rem & 15;
  float pos[3]; pos[0]=(float)f; pos[1]=(float)hh; pos[2]=(float)ww;
#pragma unroll
  for (int c=0;c<3;c++)
#pragma unroll
    for (int i=0;i<10;i++){
      float inv = exp2f(-(float)i * 1.3287712379549449f);  // 10000^(-i/10)
      float s, co;
      sincosf(pos[c]*inv, &s, &co);
      tab[n*30 + c*10 + i] = make_float2(co, s);
    }
}

// ---------------- fused QKV GEMM: A(8192x1024) @ {Wq,Wk,Wv}^T ----------------
// mat = blockIdx.x>>3.  Q,K -> (B,H,N,64) bf16.  V -> VT_perm (B,H,64,N) bf16,
// key index sigma-permuted (swap bits 2<->3, applied as 2-bit swap of g in the
// LDS bounce), stored via coalesced 128B row stores.
__global__ __launch_bounds__(256) void k_gemm_qkv(const unsigned short* __restrict__ A,
                                                  const unsigned short* __restrict__ wq,
                                                  const unsigned short* __restrict__ wk,
                                                  const unsigned short* __restrict__ wv,
                                                  const float* __restrict__ bq,
                                                  const float* __restrict__ bk,
                                                  const float* __restrict__ bv,
                                                  unsigned short* __restrict__ Qb,
                                                  unsigned short* __restrict__ Kb,
                                                  unsigned short* __restrict__ VTb)
{
  __shared__ unsigned short SM[8192];     // As = SM[0..4095], Bs = SM[4096..8191]
  unsigned short* As = SM;
  unsigned short* Bs = SM + 4096;
  const int tid = threadIdx.x, lane = tid & 63, w = tid >> 6;
  const int mat = blockIdx.x >> 3;
  const int nt  = (blockIdx.x & 7)*128;
  const int mt  = blockIdx.y*128;
  const unsigned short* Wt  = (mat==0)? wq : (mat==1)? wk : wv;
  const float*          bias= (mat==0)? bq : (mat==1)? bk : bv;
  const int wm = (w >> 1)*64, wn = (w & 1)*64;
  const int qc = lane & 15, g = lane >> 4;
  f32x4 acc[4][4] = {};

  const unsigned short* gA = A  + (size_t)(mt + w*32 + (lane>>2))*DM_ + (lane&3)*8;
  const unsigned short* gB = Wt + (size_t)(nt + w*32 + (lane>>2))*DM_ + (lane&3)*8;
  unsigned short* lA = &As[(w*32)*32];
  unsigned short* lB = &Bs[(w*32)*32];

  for (int k0 = 0; k0 < DM_; k0 += 32){
    gll16(gA + k0,           lA);
    gll16(gA + k0 + 16*DM_,  lA + 16*32);
    gll16(gB + k0,           lB);
    gll16(gB + k0 + 16*DM_,  lB + 16*32);
    __syncthreads();
    bf16x8 af[4], bfr[4];
#pragma unroll
    for (int m=0;m<4;m++) af[m]  = *(const bf16x8*)&As[(wm + m*16 + qc)*32 + g*8];
#pragma unroll
    for (int n=0;n<4;n++) bfr[n] = *(const bf16x8*)&Bs[(wn + n*16 + qc)*32 + g*8];
#pragma unroll
    for (int m=0;m<4;m++)
#pragma unroll
      for (int n=0;n<4;n++)
        acc[m][n] = __builtin_amdgcn_mfma_f32_16x16x32_bf16(af[m], bfr[n], acc[m][n], 0,0,0);
    __syncthreads();
  }

  if (mat < 2){
    unsigned short* out = (mat==0)? Qb : Kb;
#pragma unroll
    for (int n=0;n<4;n++){
      int col = nt + wn + n*16 + qc;
      float bv_ = bias[col];
      int hh = col >> 6, d = col & 63;
#pragma unroll
      for (int m=0;m<4;m++){
#pragma unroll
        for (int r=0;r<4;r++){
          int mrow = mt + wm + m*16 + g*4 + r;
          size_t idx = (((size_t)(mrow >> 11)*H_ + hh)*NS_ + (mrow & (NS_-1)))*HD_ + d;
          out[idx] = f2bf(acc[m][n][r] + bv_);
        }
      }
    }
  } else {
    // VT epilogue: LDS bounce (sigma applied via g-bit swap) + coalesced stores
    const int b = mt >> 11, ntk0 = mt & (NS_-1);
    const int gp = ((g & 1) << 1) | (g >> 1);   // swap bits of g = sigma on token bits 2,3
#pragma unroll
    for (int ph = 0; ph < 2; ++ph){
      __syncthreads();
      if ((w >> 1) == ph){                      // warps owning tokens ph*64..ph*64+63
#pragma unroll
        for (int n=0;n<4;n++){
          int dcol = wn + n*16 + qc;            // 0..127 block-local d-column
          float bv_ = bias[nt + dcol];
#pragma unroll
          for (int m=0;m<4;m++){
            ushort4 o;
            o.x = f2bf(acc[m][n][0] + bv_);
            o.y = f2bf(acc[m][n][1] + bv_);
            o.z = f2bf(acc[m][n][2] + bv_);
            o.w = f2bf(acc[m][n][3] + bv_);
            *(ushort4*)(SM + dcol*64 + m*16 + gp*4) = o;
          }
        }
      }
      __syncthreads();
      int row = tid >> 1, hf = tid & 1;         // 128 d-rows, 2 half-rows of 32 tokens
      int hh = (nt + row) >> 6, d = (nt + row) & 63;
      unsigned short* dst = VTb + ((size_t)(b*H_ + hh)*HD_ + d)*NS_ + ntk0 + ph*64 + hf*32;
      const unsigned short* srcl = SM + row*64 + hf*32;
#pragma unroll
      for (int j=0;j<4;j++)
        *(uint4*)(dst + j*8) = *(const uint4*)(srcl + j*8);
    }
  }
}

// ---------------- in-place RoPE on Q,K; Q scaled by 0.125*log2(e) ----------------
#define QSCALE 0.18033688011112042f   // 0.125 * log2(e): softmax runs in log2 units
__global__ void k_rope(unsigned short* __restrict__ Qb, unsigned short* __restrict__ Kb,
                       const float2* __restrict__ tab)
{
  const int t = threadIdx.x;
  const int d4 = (t & 15)*4;
  const long gtok = (long)blockIdx.x*16 + (t >> 4);
  size_t base = (size_t)gtok*HD_ + d4;
  if (d4 >= 60){
    ushort4 v = *(ushort4*)(Qb + base);
    ushort4 o;
    o.x = f2bf(bf2f(v.x)*QSCALE); o.y = f2bf(bf2f(v.y)*QSCALE);
    o.z = f2bf(bf2f(v.z)*QSCALE); o.w = f2bf(bf2f(v.w)*QSCALE);
    *(ushort4*)(Qb + base) = o;
    return;
  }
  const int n = (int)(gtok & (NS_-1));
  const int c = d4 / 20;
  const int dd = d4 - c*20;
  const float2* tb = tab + n*30 + c*10;
  float2 cs0 = tb[(dd+0) % 10];
  float2 cs1 = tb[(dd+1) % 10];
  float2 cs2 = tb[(dd+2) % 10];
  float2 cs3 = tb[(dd+3) % 10];
#pragma unroll
  for (int which = 0; which < 2; which++){
    unsigned short* P = which ? Kb : Qb;
    float sc = which ? 1.f : QSCALE;
    ushort4 v = *(ushort4*)(P + base);
    float x0=bf2f(v.x), x1=bf2f(v.y), x2=bf2f(v.z), x3=bf2f(v.w);
    ushort4 o;
    o.x = f2bf((x0*cs0.x - x1*cs0.y)*sc);
    o.y = f2bf((x1*cs1.x + x0*cs1.y)*sc);
    o.z = f2bf((x2*cs2.x - x3*cs2.y)*sc);
    o.w = f2bf((x3*cs3.x + x2*cs3.y)*sc);
    *(ushort4*)(P + base) = o;
  }
}

// ---------------- 4-warp flash attention, 32x32 MFMA, swapped QK^T ----------------
// grid (bh=64, qblk=16): heads XCD-affine (id mod 8); 1024 blocks = 4 blocks/CU
// (128KB LDS) for barrier-stall overlap. Softmax in log2 units via bare
// v_exp_f32; P via v_cvt_pk_bf16_f32 with l accumulated FROM the truncated
// values (ratio-consistent, unbiased). V read is a single b128 (sigma-permuted
// VT). setprio(1) around MFMA clusters.
__global__ __launch_bounds__(256, 4) void k_attn(const unsigned short* __restrict__ Q,
                                                 const unsigned short* __restrict__ K,
                                                 const unsigned short* __restrict__ VT,
                                                 unsigned short* __restrict__ ctxout)
{
  __shared__ __attribute__((aligned(16))) char smem[32768]; // 2 bufs x (8KB K + 8KB VT)
  const int tid  = threadIdx.x;
  const int lane = tid & 63, w = tid >> 6;       // w = 0..3
  const int qcol = lane & 31, h = lane >> 5;
  const int sw   = (lane & 7) << 4;
  const int bh   = blockIdx.x;
  const int q0   = blockIdx.y*128 + w*32;

  const unsigned short* Qp = Q  + ((size_t)bh*NS_ + q0)*HD_;
  const unsigned short* Kp = K  + (size_t)bh*NS_*HD_;
  const unsigned short* Vp = VT + (size_t)bh*HD_*NS_;

  // staging map: thread t covers LDS rows (tid>>3) and (tid>>3)+32, chunk tc
  const int trow = tid >> 3;                 // 0..31
  const int tc   = (tid & 7) ^ (trow & 7);   // (trow+32)&7 == trow&7

  bf16x8 qf[4];
#pragma unroll
  for (int i=0;i<4;i++)
    qf[i] = *(const bf16x8*)(Qp + (size_t)qcol*HD_ + 16*i + 8*h);

  // stage tile 0 into buffer 0
  {
    const unsigned short* gk = Kp + (size_t)trow*HD_ + tc*8;
    const unsigned short* gv = Vp + (size_t)trow*NS_ + tc*8;
    gll16(gk,          smem + w*1024);
    gll16(gk + 32*HD_, smem + 4096 + w*1024);
    gll16(gv,          smem + 8192 + w*1024);
    gll16(gv + 32*NS_, smem + 8192 + 4096 + w*1024);
  }

  f32x16 ctx0 = {}, ctx1 = {};
  float mrun = -1e30f, lp = 0.f;

  for (int t = 0; t < NS_/64; ++t){
    const int curo = (t & 1) * 16384;
    __syncthreads();                      // barrier drains vmcnt: stage(cur) complete
    if (t + 1 < NS_/64){
      const int kb = (t+1)*64;
      const int nxt = ((t+1) & 1) * 16384;
      const unsigned short* gk = Kp + (size_t)(kb + trow)*HD_ + tc*8;
      const unsigned short* gv = Vp + (size_t)trow*NS_ + kb + tc*8;
      gll16(gk,          smem + nxt + w*1024);
      gll16(gk + 32*HD_, smem + nxt + 4096 + w*1024);
      gll16(gv,          smem + nxt + 8192 + w*1024);
      gll16(gv + 32*NS_, smem + nxt + 8192 + 4096 + w*1024);
    }
    const char* kls = smem + curo;
    const char* vls = smem + curo + 8192;

#pragma unroll
    for (int s = 0; s < 2; ++s){          // two 32-key subtiles
      f32x16 st = {};
      __builtin_amdgcn_s_setprio(1);
#pragma unroll
      for (int i=0;i<4;i++){
        bf16x8 kf = *(const bf16x8*)(kls + ((((32*s + qcol)*128) + 32*i + 16*h) ^ sw));
        st = __builtin_amdgcn_mfma_f32_32x32x16_bf16(kf, qf[i], st, 0,0,0);
      }
      __builtin_amdgcn_s_setprio(0);
      // ---- local max (max3 tree), defer-max in log2 units ----
      float a0 = fmaxf(fmaxf(st[0],  st[1]),  st[2]);
      float a1 = fmaxf(fmaxf(st[3],  st[4]),  st[5]);
      float a2 = fmaxf(fmaxf(st[6],  st[7]),  st[8]);
      float a3 = fmaxf(fmaxf(st[9],  st[10]), st[11]);
      float a4 = fmaxf(fmaxf(st[12], st[13]), st[14]);
      float tm = fmaxf(fmaxf(fmaxf(a0,a1),a2), fmaxf(fmaxf(a3,a4),st[15]));
      if (!__all(tm - mrun <= 11.5f)){
        float tp = fmaxf(tm, __shfl_xor(tm, 32));
        float mnew = fmaxf(mrun, tp);
        float alpha = exp2a(mrun - mnew);
        lp *= alpha;
#pragma unroll
        for (int r=0;r<16;r++){ ctx0[r]*=alpha; ctx1[r]*=alpha; }
        mrun = mnew;
      }
      // ---- P: bare v_exp + packed bf16 cvt; lp from the SAME truncated values ----
      unsigned u[8];
      float ps = 0.f;
#pragma unroll
      for (int r=0;r<8;r++){
        float ea = exp2a(st[2*r]   - mrun);
        float eb = exp2a(st[2*r+1] - mrun);
        unsigned uu = cvtpk(ea, eb);
        u[r] = uu;
        union { unsigned q; float f; } lo, hi;
        lo.q = uu << 16; hi.q = uu & 0xFFFF0000u;
        ps += lo.f + hi.f;
      }
      lp += ps;
      bf16x8 pf0 = __builtin_bit_cast(bf16x8, make_uint4(u[0],u[1],u[2],u[3]));
      bf16x8 pf1 = __builtin_bit_cast(bf16x8, make_uint4(u[4],u[5],u[6],u[7]));

      // ---- PV: single b128 V fragment (sigma-permuted storage) ----
      __builtin_amdgcn_s_setprio(1);
#pragma unroll
      for (int kc=0; kc<2; ++kc){
        const bf16x8 pf = kc ? pf1 : pf0;
        bf16x8 vf0 = *(const bf16x8*)(vls + ((qcol)*128      + ((64*s + 32*kc + 16*h) ^ sw)));
        ctx0 = __builtin_amdgcn_mfma_f32_32x32x16_bf16(vf0, pf, ctx0, 0,0,0);
        bf16x8 vf1 = *(const bf16x8*)(vls + ((32 + qcol)*128 + ((64*s + 32*kc + 16*h) ^ sw)));
        ctx1 = __builtin_amdgcn_mfma_f32_32x32x16_bf16(vf1, pf, ctx1, 0,0,0);
      }
      __builtin_amdgcn_s_setprio(0);
    }
  }

  float lsum = lp + __shfl_xor(lp, 32);
  float linv = 1.f / lsum;
  __syncthreads();                         // all warps done reading K/V LDS
  char* reg = smem + w*4096;               // 4KB per warp: [32 q][64 d] bf16
#pragma unroll
  for (int rq=0; rq<4; ++rq){
    int db0 = 8*rq + 4*h;
    uint2 v0, v1;
    v0.x = pk2(ctx0[4*rq+0]*linv, ctx0[4*rq+1]*linv);
    v0.y = pk2(ctx0[4*rq+2]*linv, ctx0[4*rq+3]*linv);
    v1.x = pk2(ctx1[4*rq+0]*linv, ctx1[4*rq+1]*linv);
    v1.y = pk2(ctx1[4*rq+2]*linv, ctx1[4*rq+3]*linv);
    *(uint2*)(reg + qcol*128 + db0*2)      = v0;
    *(uint2*)(reg + qcol*128 + (32+db0)*2) = v1;
  }
  __syncthreads();
  const int b = bh >> 4, head = bh & 15;
  unsigned short* outp = ctxout + ((size_t)b*NS_ + q0)*DM_ + head*HD_;
#pragma unroll
  for (int p=0;p<4;p++){
    int row = p*8 + (lane>>3);
    uint4 v = *(const uint4*)(reg + row*128 + (lane&7)*16);
    *(uint4*)(outp + (size_t)row*DM_ + (lane&7)*8) = v;
  }
}

// ---------------- output projection GEMM (fp32 out) ----------------
__global__ __launch_bounds__(256) void k_gemm_o(const unsigned short* __restrict__ A,
                                                const unsigned short* __restrict__ Wt,
                                                const float* __restrict__ bias,
                                                float* __restrict__ out)
{
  __shared__ unsigned short As[128*32];
  __shared__ unsigned short Bs[128*32];
  const int tid = threadIdx.x, lane = tid & 63, w = tid >> 6;
  const int mt = blockIdx.y*128, nt = blockIdx.x*128;
  const int wm = (w >> 1)*64, wn = (w & 1)*64;
  const int qc = lane & 15, g = lane >> 4;
  f32x4 acc[4][4] = {};

  const unsigned short* gA = A  + (size_t)(mt + w*32 + (lane>>2))*DM_ + (lane&3)*8;
  const unsigned short* gB = Wt + (size_t)(nt + w*32 + (lane>>2))*DM_ + (lane&3)*8;
  unsigned short* lA = &As[(w*32)*32];
  unsigned short* lB = &Bs[(w*32)*32];

  for (int k0 = 0; k0 < DM_; k0 += 32){
    gll16(gA + k0,           lA);
    gll16(gA + k0 + 16*DM_,  lA + 16*32);
    gll16(gB + k0,           lB);
    gll16(gB + k0 + 16*DM_,  lB + 16*32);
    __syncthreads();
    bf16x8 af[4], bfr[4];
#pragma unroll
    for (int m=0;m<4;m++) af[m]  = *(const bf16x8*)&As[(wm + m*16 + qc)*32 + g*8];
#pragma unroll
    for (int n=0;n<4;n++) bfr[n] = *(const bf16x8*)&Bs[(wn + n*16 + qc)*32 + g*8];
#pragma unroll
    for (int m=0;m<4;m++)
#pragma unroll
      for (int n=0;n<4;n++)
        acc[m][n] = __builtin_amdgcn_mfma_f32_16x16x32_bf16(af[m], bfr[n], acc[m][n], 0,0,0);
    __syncthreads();
  }

#pragma unroll
  for (int n=0;n<4;n++){
    int col = nt + wn + n*16 + qc;
    float bv = bias[col];
#pragma unroll
    for (int m=0;m<4;m++){
#pragma unroll
      for (int r=0;r<4;r++){
        int mrow = mt + wm + m*16 + g*4 + r;
        out[(size_t)mrow*DM_ + col] = acc[m][n][r] + bv;
      }
    }
  }
}

extern "C" void kernel_launch(void* const* d_in, const int* in_sizes, int n_in,
                              void* d_out, int out_size, void* d_ws, size_t ws_size,
                              hipStream_t stream)
{
  const float* hs = (const float*)d_in[0];
  const float* Wq = (const float*)d_in[1];
  const float* bq = (const float*)d_in[2];
  const float* Wk = (const float*)d_in[3];
  const float* bk = (const float*)d_in[4];
  const float* Wv = (const float*)d_in[5];
  const float* bv = (const float*)d_in[6];
  const float* Wo = (const float*)d_in[7];
  const float* bo = (const float*)d_in[8];

  char* ws = (char*)d_ws;
  size_t off = 0;
  auto alloc = [&](size_t b){ void* p = ws + off; off += (b + 255) & ~(size_t)255; return p; };
  unsigned short* xb  = (unsigned short*)alloc((size_t)MTOT*DM_*2);
  unsigned short* wqt = (unsigned short*)alloc((size_t)DM_*DM_*2);
  unsigned short* wkt = (unsigned short*)alloc((size_t)DM_*DM_*2);
  unsigned short* wvt = (unsigned short*)alloc((size_t)DM_*DM_*2);
  unsigned short* wot = (unsigned short*)alloc((size_t)DM_*DM_*2);
  float2*         tab = (float2*)alloc((size_t)NS_*30*sizeof(float2));
  unsigned short* Qb  = (unsigned short*)alloc((size_t)MTOT*DM_*2);
  unsigned short* Kb  = (unsigned short*)alloc((size_t)MTOT*DM_*2);
  unsigned short* VTb = (unsigned short*)alloc((size_t)MTOT*DM_*2);
  unsigned short* cxb = (unsigned short*)alloc((size_t)MTOT*DM_*2);

  k_cast_x<<<dim3(MTOT*DM_/1024), dim3(256), 0, stream>>>(hs, xb);
  k_wt<<<dim3(16,16), dim3(256), 0, stream>>>(Wq, wqt);
  k_wt<<<dim3(16,16), dim3(256), 0, stream>>>(Wk, wkt);
  k_wt<<<dim3(16,16), dim3(256), 0, stream>>>(Wv, wvt);
  k_wt<<<dim3(16,16), dim3(256), 0, stream>>>(Wo, wot);
  k_tab<<<dim3(32), dim3(64), 0, stream>>>(tab);

  k_gemm_qkv<<<dim3(24,64), dim3(256), 0, stream>>>(xb, wqt, wkt, wvt, bq, bk, bv,
                                                    Qb, Kb, VTb);

  k_rope<<<dim3(64*NS_/16), dim3(256), 0, stream>>>(Qb, Kb, tab);

  k_attn<<<dim3(64, 16), dim3(256), 0, stream>>>(Qb, Kb, VTb, cxb);

  k_gemm_o<<<dim3(8,64), dim3(256), 0, stream>>>(cxb, wot, bo, (float*)d_out);
}

// Round 7
// 248.034 us; speedup vs baseline: 1.2080x; 1.2080x over previous
//
#include <hip/hip_runtime.h>
#include <stdint.h>

#define H_   16
#define NS_  2048
#define B_   4
#define DM_  1024
#define HD_  64
#define MTOT (B_*NS_)   // 8192 tokens

typedef __attribute__((ext_vector_type(8)))  short bf16x8;
typedef __attribute__((ext_vector_type(4)))  float f32x4;
typedef __attribute__((ext_vector_type(16))) float f32x16;

__device__ __forceinline__ unsigned short f2bf(float f){
  union { float f; unsigned u; } v; v.f = f;
  unsigned r = v.u + 0x7FFFu + ((v.u >> 16) & 1u);
  return (unsigned short)(r >> 16);
}
__device__ __forceinline__ float bf2f(unsigned short u){
  union { unsigned u; float f; } v; v.u = ((unsigned)u) << 16;
  return v.f;
}
__device__ __forceinline__ unsigned pk2(float a, float b){
  return (unsigned)f2bf(a) | ((unsigned)f2bf(b) << 16);
}
__device__ __forceinline__ unsigned cvtpk(float a, float b){
  unsigned r;
  asm("v_cvt_pk_bf16_f32 %0, %1, %2" : "=v"(r) : "v"(a), "v"(b));
  return r;
}
__device__ __forceinline__ float exp2a(float x){   // bare v_exp_f32 (2^x)
  float r;
  asm("v_exp_f32 %0, %1" : "=v"(r) : "v"(x));
  return r;
}
__device__ __forceinline__ void gll16(const void* g, void* l){
  __builtin_amdgcn_global_load_lds(
      (const __attribute__((address_space(1))) unsigned int*)g,
      (__attribute__((address_space(3))) unsigned int*)l,
      16, 0, 0);
}

// ---------------- cast hidden_states fp32 -> bf16 ----------------
__global__ void k_cast_x(const float* __restrict__ x, unsigned short* __restrict__ xb){
  long i = ((long)blockIdx.x*256 + threadIdx.x)*4;
  float4 v = *(const float4*)(x + i);
  ushort4 o; o.x=f2bf(v.x); o.y=f2bf(v.y); o.z=f2bf(v.z); o.w=f2bf(v.w);
  *(ushort4*)(xb + i) = o;
}

// ---------------- transpose-cast 4 weights: W[k][n] fp32 -> Wt[n][k] bf16 ----------------
__global__ void k_wt4(const float* __restrict__ W0, const float* __restrict__ W1,
                      const float* __restrict__ W2, const float* __restrict__ W3,
                      unsigned short* __restrict__ T0, unsigned short* __restrict__ T1,
                      unsigned short* __restrict__ T2, unsigned short* __restrict__ T3){
  __shared__ float tile[64][65];
  const int z = blockIdx.z;
  const float* W = (z==0)? W0 : (z==1)? W1 : (z==2)? W2 : W3;
  unsigned short* Wt = (z==0)? T0 : (z==1)? T1 : (z==2)? T2 : T3;
  int kt = blockIdx.y*64, nt = blockIdx.x*64;
  int t = threadIdx.x;
  int r = t >> 4, c4 = (t & 15)*4;
#pragma unroll
  for (int i=0;i<4;i++){
    int k = r + i*16;
    float4 v = *(const float4*)(W + (size_t)(kt + k)*DM_ + nt + c4);
    tile[k][c4] = v.x; tile[k][c4+1]=v.y; tile[k][c4+2]=v.z; tile[k][c4+3]=v.w;
  }
  __syncthreads();
#pragma unroll
  for (int i=0;i<4;i++){
    int n = r + i*16;
    ushort4 o;
    o.x = f2bf(tile[c4+0][n]); o.y = f2bf(tile[c4+1][n]);
    o.z = f2bf(tile[c4+2][n]); o.w = f2bf(tile[c4+3][n]);
    *(ushort4*)(Wt + (size_t)(nt + n)*DM_ + kt + c4) = o;
  }
}

// ---------------- RoPE sin/cos table ----------------
__global__ void k_tab(float2* __restrict__ tab){
  int n = blockIdx.x*64 + threadIdx.x;
  int f = n >> 8, rem = n & 255, hh = rem >> 4, ww = rem & 15;
  float pos[3]; pos[0]=(float)f; pos[1]=(float)hh; pos[2]=(float)ww;
#pragma unroll
  for (int c=0;c<3;c++)
#pragma unroll
    for (int i=0;i<10;i++){
      float inv = exp2f(-(float)i * 1.3287712379549449f);  // 10000^(-i/10)
      float s, co;
      sincosf(pos[c]*inv, &s, &co);
      tab[n*30 + c*10 + i] = make_float2(co, s);
    }
}

// ---------------- fused QKV GEMM (r5-proven): A @ {Wq,Wk,Wv}^T ----------------
// mat = blockIdx.x>>3.  Q,K -> (B,H,N,64) bf16.  V -> VT_perm (B,H,64,N) bf16
// with key index sigma-permuted (swap bits 2<->3) along N (scatter epilogue;
// 8B stores at 4KB stride are L2-absorbed — measured faster than LDS bounce).
__global__ __launch_bounds__(256) void k_gemm_qkv(const unsigned short* __restrict__ A,
                                                  const unsigned short* __restrict__ wq,
                                                  const unsigned short* __restrict__ wk,
                                                  const unsigned short* __restrict__ wv,
                                                  const float* __restrict__ bq,
                                                  const float* __restrict__ bk,
                                                  const float* __restrict__ bv,
                                                  unsigned short* __restrict__ Qb,
                                                  unsigned short* __restrict__ Kb,
                                                  unsigned short* __restrict__ VTb)
{
  __shared__ unsigned short As[128*32];
  __shared__ unsigned short Bs[128*32];
  const int tid = threadIdx.x, lane = tid & 63, w = tid >> 6;
  const int mat = blockIdx.x >> 3;
  const int nt  = (blockIdx.x & 7)*128;
  const int mt  = blockIdx.y*128;
  const unsigned short* Wt  = (mat==0)? wq : (mat==1)? wk : wv;
  const float*          bias= (mat==0)? bq : (mat==1)? bk : bv;
  const int wm = (w >> 1)*64, wn = (w & 1)*64;
  const int qc = lane & 15, g = lane >> 4;
  f32x4 acc[4][4] = {};

  const unsigned short* gA = A  + (size_t)(mt + w*32 + (lane>>2))*DM_ + (lane&3)*8;
  const unsigned short* gB = Wt + (size_t)(nt + w*32 + (lane>>2))*DM_ + (lane&3)*8;
  unsigned short* lA = &As[(w*32)*32];
  unsigned short* lB = &Bs[(w*32)*32];

  for (int k0 = 0; k0 < DM_; k0 += 32){
    gll16(gA + k0,           lA);
    gll16(gA + k0 + 16*DM_,  lA + 16*32);
    gll16(gB + k0,           lB);
    gll16(gB + k0 + 16*DM_,  lB + 16*32);
    __syncthreads();
    bf16x8 af[4], bfr[4];
#pragma unroll
    for (int m=0;m<4;m++) af[m]  = *(const bf16x8*)&As[(wm + m*16 + qc)*32 + g*8];
#pragma unroll
    for (int n=0;n<4;n++) bfr[n] = *(const bf16x8*)&Bs[(wn + n*16 + qc)*32 + g*8];
#pragma unroll
    for (int m=0;m<4;m++)
#pragma unroll
      for (int n=0;n<4;n++)
        acc[m][n] = __builtin_amdgcn_mfma_f32_16x16x32_bf16(af[m], bfr[n], acc[m][n], 0,0,0);
    __syncthreads();
  }

  if (mat < 2){
    unsigned short* out = (mat==0)? Qb : Kb;
#pragma unroll
    for (int n=0;n<4;n++){
      int col = nt + wn + n*16 + qc;
      float bv_ = bias[col];
      int hh = col >> 6, d = col & 63;
#pragma unroll
      for (int m=0;m<4;m++){
#pragma unroll
        for (int r=0;r<4;r++){
          int mrow = mt + wm + m*16 + g*4 + r;
          size_t idx = (((size_t)(mrow >> 11)*H_ + hh)*NS_ + (mrow & (NS_-1)))*HD_ + d;
          out[idx] = f2bf(acc[m][n][r] + bv_);
        }
      }
    }
  } else {
#pragma unroll
    for (int n=0;n<4;n++){
      int col = nt + wn + n*16 + qc;
      float bv_ = bias[col];
      int hh = col >> 6, d = col & 63;
#pragma unroll
      for (int m=0;m<4;m++){
        int mrow0 = mt + wm + m*16 + g*4;     // r=0..3 consecutive tokens
        int b = mrow0 >> 11, ntk = mrow0 & (NS_-1);
        int pos = (ntk & ~12) | ((ntk & 4) << 1) | ((ntk & 8) >> 1);  // swap bits 2,3
        ushort4 o;
        o.x = f2bf(acc[m][n][0] + bv_);
        o.y = f2bf(acc[m][n][1] + bv_);
        o.z = f2bf(acc[m][n][2] + bv_);
        o.w = f2bf(acc[m][n][3] + bv_);
        *(ushort4*)(VTb + (((size_t)(b*H_ + hh)*HD_ + d)*NS_ + pos)) = o;
      }
    }
  }
}

// ---------------- in-place RoPE on Q,K; Q scaled by 0.125*log2(e) ----------------
#define QSCALE 0.18033688011112042f   // 0.125 * log2(e): softmax runs in log2 units
__global__ void k_rope(unsigned short* __restrict__ Qb, unsigned short* __restrict__ Kb,
                       const float2* __restrict__ tab)
{
  const int t = threadIdx.x;
  const int d4 = (t & 15)*4;
  const long gtok = (long)blockIdx.x*16 + (t >> 4);
  size_t base = (size_t)gtok*HD_ + d4;
  if (d4 >= 60){
    ushort4 v = *(ushort4*)(Qb + base);
    ushort4 o;
    o.x = f2bf(bf2f(v.x)*QSCALE); o.y = f2bf(bf2f(v.y)*QSCALE);
    o.z = f2bf(bf2f(v.z)*QSCALE); o.w = f2bf(bf2f(v.w)*QSCALE);
    *(ushort4*)(Qb + base) = o;
    return;
  }
  const int n = (int)(gtok & (NS_-1));
  const int c = d4 / 20;
  const int dd = d4 - c*20;
  const float2* tb = tab + n*30 + c*10;
  float2 cs0 = tb[(dd+0) % 10];
  float2 cs1 = tb[(dd+1) % 10];
  float2 cs2 = tb[(dd+2) % 10];
  float2 cs3 = tb[(dd+3) % 10];
#pragma unroll
  for (int which = 0; which < 2; which++){
    unsigned short* P = which ? Kb : Qb;
    float sc = which ? 1.f : QSCALE;
    ushort4 v = *(ushort4*)(P + base);
    float x0=bf2f(v.x), x1=bf2f(v.y), x2=bf2f(v.z), x3=bf2f(v.w);
    ushort4 o;
    o.x = f2bf((x0*cs0.x - x1*cs0.y)*sc);
    o.y = f2bf((x1*cs1.x + x0*cs1.y)*sc);
    o.z = f2bf((x2*cs2.x - x3*cs2.y)*sc);
    o.w = f2bf((x3*cs3.x + x2*cs3.y)*sc);
    *(ushort4*)(P + base) = o;
  }
}

// ---------------- 4-warp flash attention, 32x32 MFMA, swapped QK^T ----------------
// grid (bh=64, qblk=16): heads XCD-affine (id mod 8); 1024 blocks = 4 blocks/CU.
// Softmax in log2 units via bare v_exp_f32; P via v_cvt_pk_bf16_f32 with l
// accumulated FROM the truncated values (ratio-consistent). V read is a single
// b128 (sigma-permuted VT). setprio(1) around MFMA clusters.
__global__ __launch_bounds__(256, 4) void k_attn(const unsigned short* __restrict__ Q,
                                                 const unsigned short* __restrict__ K,
                                                 const unsigned short* __restrict__ VT,
                                                 unsigned short* __restrict__ ctxout)
{
  __shared__ __attribute__((aligned(16))) char smem[32768]; // 2 bufs x (8KB K + 8KB VT)
  const int tid  = threadIdx.x;
  const int lane = tid & 63, w = tid >> 6;       // w = 0..3
  const int qcol = lane & 31, h = lane >> 5;
  const int sw   = (lane & 7) << 4;
  const int bh   = blockIdx.x;
  const int q0   = blockIdx.y*128 + w*32;

  const unsigned short* Qp = Q  + ((size_t)bh*NS_ + q0)*HD_;
  const unsigned short* Kp = K  + (size_t)bh*NS_*HD_;
  const unsigned short* Vp = VT + (size_t)bh*HD_*NS_;

  // staging map: thread t covers LDS rows (tid>>3) and (tid>>3)+32, chunk tc
  const int trow = tid >> 3;                 // 0..31
  const int tc   = (tid & 7) ^ (trow & 7);   // (trow+32)&7 == trow&7

  bf16x8 qf[4];
#pragma unroll
  for (int i=0;i<4;i++)
    qf[i] = *(const bf16x8*)(Qp + (size_t)qcol*HD_ + 16*i + 8*h);

  // stage tile 0 into buffer 0
  {
    const unsigned short* gk = Kp + (size_t)trow*HD_ + tc*8;
    const unsigned short* gv = Vp + (size_t)trow*NS_ + tc*8;
    gll16(gk,          smem + w*1024);
    gll16(gk + 32*HD_, smem + 4096 + w*1024);
    gll16(gv,          smem + 8192 + w*1024);
    gll16(gv + 32*NS_, smem + 8192 + 4096 + w*1024);
  }

  f32x16 ctx0 = {}, ctx1 = {};
  float mrun = -1e30f, lp = 0.f;

  for (int t = 0; t < NS_/64; ++t){
    const int curo = (t & 1) * 16384;
    __syncthreads();                      // barrier drains vmcnt: stage(cur) complete
    if (t + 1 < NS_/64){
      const int kb = (t+1)*64;
      const int nxt = ((t+1) & 1) * 16384;
      const unsigned short* gk = Kp + (size_t)(kb + trow)*HD_ + tc*8;
      const unsigned short* gv = Vp + (size_t)trow*NS_ + kb + tc*8;
      gll16(gk,          smem + nxt + w*1024);
      gll16(gk + 32*HD_, smem + nxt + 4096 + w*1024);
      gll16(gv,          smem + nxt + 8192 + w*1024);
      gll16(gv + 32*NS_, smem + nxt + 8192 + 4096 + w*1024);
    }
    const char* kls = smem + curo;
    const char* vls = smem + curo + 8192;

#pragma unroll
    for (int s = 0; s < 2; ++s){          // two 32-key subtiles
      f32x16 st = {};
      __builtin_amdgcn_s_setprio(1);
#pragma unroll
      for (int i=0;i<4;i++){
        bf16x8 kf = *(const bf16x8*)(kls + ((((32*s + qcol)*128) + 32*i + 16*h) ^ sw));
        st = __builtin_amdgcn_mfma_f32_32x32x16_bf16(kf, qf[i], st, 0,0,0);
      }
      __builtin_amdgcn_s_setprio(0);
      // ---- local max (max3 tree), defer-max in log2 units ----
      float a0 = fmaxf(fmaxf(st[0],  st[1]),  st[2]);
      float a1 = fmaxf(fmaxf(st[3],  st[4]),  st[5]);
      float a2 = fmaxf(fmaxf(st[6],  st[7]),  st[8]);
      float a3 = fmaxf(fmaxf(st[9],  st[10]), st[11]);
      float a4 = fmaxf(fmaxf(st[12], st[13]), st[14]);
      float tm = fmaxf(fmaxf(fmaxf(a0,a1),a2), fmaxf(fmaxf(a3,a4),st[15]));
      if (!__all(tm - mrun <= 11.5f)){
        float tp = fmaxf(tm, __shfl_xor(tm, 32));
        float mnew = fmaxf(mrun, tp);
        float alpha = exp2a(mrun - mnew);
        lp *= alpha;
#pragma unroll
        for (int r=0;r<16;r++){ ctx0[r]*=alpha; ctx1[r]*=alpha; }
        mrun = mnew;
      }
      // ---- P: bare v_exp + packed bf16 cvt; lp from the SAME truncated values ----
      unsigned u[8];
      float ps = 0.f;
#pragma unroll
      for (int r=0;r<8;r++){
        float ea = exp2a(st[2*r]   - mrun);
        float eb = exp2a(st[2*r+1] - mrun);
        unsigned uu = cvtpk(ea, eb);
        u[r] = uu;
        union { unsigned q; float f; } lo, hi;
        lo.q = uu << 16; hi.q = uu & 0xFFFF0000u;
        ps += lo.f + hi.f;
      }
      lp += ps;
      bf16x8 pf0 = __builtin_bit_cast(bf16x8, make_uint4(u[0],u[1],u[2],u[3]));
      bf16x8 pf1 = __builtin_bit_cast(bf16x8, make_uint4(u[4],u[5],u[6],u[7]));

      // ---- PV: single b128 V fragment (sigma-permuted storage) ----
      __builtin_amdgcn_s_setprio(1);
#pragma unroll
      for (int kc=0; kc<2; ++kc){
        const bf16x8 pf = kc ? pf1 : pf0;
        bf16x8 vf0 = *(const bf16x8*)(vls + ((qcol)*128      + ((64*s + 32*kc + 16*h) ^ sw)));
        ctx0 = __builtin_amdgcn_mfma_f32_32x32x16_bf16(vf0, pf, ctx0, 0,0,0);
        bf16x8 vf1 = *(const bf16x8*)(vls + ((32 + qcol)*128 + ((64*s + 32*kc + 16*h) ^ sw)));
        ctx1 = __builtin_amdgcn_mfma_f32_32x32x16_bf16(vf1, pf, ctx1, 0,0,0);
      }
      __builtin_amdgcn_s_setprio(0);
    }
  }

  float lsum = lp + __shfl_xor(lp, 32);
  float linv = 1.f / lsum;
  __syncthreads();                         // all warps done reading K/V LDS
  char* reg = smem + w*4096;               // 4KB per warp: [32 q][64 d] bf16
#pragma unroll
  for (int rq=0; rq<4; ++rq){
    int db0 = 8*rq + 4*h;
    uint2 v0, v1;
    v0.x = pk2(ctx0[4*rq+0]*linv, ctx0[4*rq+1]*linv);
    v0.y = pk2(ctx0[4*rq+2]*linv, ctx0[4*rq+3]*linv);
    v1.x = pk2(ctx1[4*rq+0]*linv, ctx1[4*rq+1]*linv);
    v1.y = pk2(ctx1[4*rq+2]*linv, ctx1[4*rq+3]*linv);
    *(uint2*)(reg + qcol*128 + db0*2)      = v0;
    *(uint2*)(reg + qcol*128 + (32+db0)*2) = v1;
  }
  __syncthreads();
  const int b = bh >> 4, head = bh & 15;
  unsigned short* outp = ctxout + ((size_t)b*NS_ + q0)*DM_ + head*HD_;
#pragma unroll
  for (int p=0;p<4;p++){
    int row = p*8 + (lane>>3);
    uint4 v = *(const uint4*)(reg + row*128 + (lane&7)*16);
    *(uint4*)(outp + (size_t)row*DM_ + (lane&7)*8) = v;
  }
}

// ---------------- output projection GEMM (fp32 out) ----------------
__global__ __launch_bounds__(256) void k_gemm_o(const unsigned short* __restrict__ A,
                                                const unsigned short* __restrict__ Wt,
                                                const float* __restrict__ bias,
                                                float* __restrict__ out)
{
  __shared__ unsigned short As[128*32];
  __shared__ unsigned short Bs[128*32];
  const int tid = threadIdx.x, lane = tid & 63, w = tid >> 6;
  const int mt = blockIdx.y*128, nt = blockIdx.x*128;
  const int wm = (w >> 1)*64, wn = (w & 1)*64;
  const int qc = lane & 15, g = lane >> 4;
  f32x4 acc[4][4] = {};

  const unsigned short* gA = A  + (size_t)(mt + w*32 + (lane>>2))*DM_ + (lane&3)*8;
  const unsigned short* gB = Wt + (size_t)(nt + w*32 + (lane>>2))*DM_ + (lane&3)*8;
  unsigned short* lA = &As[(w*32)*32];
  unsigned short* lB = &Bs[(w*32)*32];

  for (int k0 = 0; k0 < DM_; k0 += 32){
    gll16(gA + k0,           lA);
    gll16(gA + k0 + 16*DM_,  lA + 16*32);
    gll16(gB + k0,           lB);
    gll16(gB + k0 + 16*DM_,  lB + 16*32);
    __syncthreads();
    bf16x8 af[4], bfr[4];
#pragma unroll
    for (int m=0;m<4;m++) af[m]  = *(const bf16x8*)&As[(wm + m*16 + qc)*32 + g*8];
#pragma unroll
    for (int n=0;n<4;n++) bfr[n] = *(const bf16x8*)&Bs[(wn + n*16 + qc)*32 + g*8];
#pragma unroll
    for (int m=0;m<4;m++)
#pragma unroll
      for (int n=0;n<4;n++)
        acc[m][n] = __builtin_amdgcn_mfma_f32_16x16x32_bf16(af[m], bfr[n], acc[m][n], 0,0,0);
    __syncthreads();
  }

#pragma unroll
  for (int n=0;n<4;n++){
    int col = nt + wn + n*16 + qc;
    float bv = bias[col];
#pragma unroll
    for (int m=0;m<4;m++){
#pragma unroll
      for (int r=0;r<4;r++){
        int mrow = mt + wm + m*16 + g*4 + r;
        out[(size_t)mrow*DM_ + col] = acc[m][n][r] + bv;
      }
    }
  }
}

extern "C" void kernel_launch(void* const* d_in, const int* in_sizes, int n_in,
                              void* d_out, int out_size, void* d_ws, size_t ws_size,
                              hipStream_t stream)
{
  const float* hs = (const float*)d_in[0];
  const float* Wq = (const float*)d_in[1];
  const float* bq = (const float*)d_in[2];
  const float* Wk = (const float*)d_in[3];
  const float* bk = (const float*)d_in[4];
  const float* Wv = (const float*)d_in[5];
  const float* bv = (const float*)d_in[6];
  const float* Wo = (const float*)d_in[7];
  const float* bo = (const float*)d_in[8];

  char* ws = (char*)d_ws;
  size_t off = 0;
  auto alloc = [&](size_t b){ void* p = ws + off; off += (b + 255) & ~(size_t)255; return p; };
  unsigned short* xb  = (unsigned short*)alloc((size_t)MTOT*DM_*2);
  unsigned short* wqt = (unsigned short*)alloc((size_t)DM_*DM_*2);
  unsigned short* wkt = (unsigned short*)alloc((size_t)DM_*DM_*2);
  unsigned short* wvt = (unsigned short*)alloc((size_t)DM_*DM_*2);
  unsigned short* wot = (unsigned short*)alloc((size_t)DM_*DM_*2);
  float2*         tab = (float2*)alloc((size_t)NS_*30*sizeof(float2));
  unsigned short* Qb  = (unsigned short*)alloc((size_t)MTOT*DM_*2);
  unsigned short* Kb  = (unsigned short*)alloc((size_t)MTOT*DM_*2);
  unsigned short* VTb = (unsigned short*)alloc((size_t)MTOT*DM_*2);
  unsigned short* cxb = (unsigned short*)alloc((size_t)MTOT*DM_*2);

  k_cast_x<<<dim3(MTOT*DM_/1024), dim3(256), 0, stream>>>(hs, xb);
  k_wt4<<<dim3(16,16,4), dim3(256), 0, stream>>>(Wq, Wk, Wv, Wo, wqt, wkt, wvt, wot);
  k_tab<<<dim3(32), dim3(64), 0, stream>>>(tab);

  k_gemm_qkv<<<dim3(24,64), dim3(256), 0, stream>>>(xb, wqt, wkt, wvt, bq, bk, bv,
                                                    Qb, Kb, VTb);

  k_rope<<<dim3(64*NS_/16), dim3(256), 0, stream>>>(Qb, Kb, tab);

  k_attn<<<dim3(64, 16), dim3(256), 0, stream>>>(Qb, Kb, VTb, cxb);

  k_gemm_o<<<dim3(8,64), dim3(256), 0, stream>>>(cxb, wot, bo, (float*)d_out);
}

// Round 8
// 239.989 us; speedup vs baseline: 1.2485x; 1.0335x over previous
//
#include <hip/hip_runtime.h>
#include <stdint.h>

#define H_   16
#define NS_  2048
#define B_   4
#define DM_  1024
#define HD_  64
#define MTOT (B_*NS_)   // 8192 tokens

typedef __attribute__((ext_vector_type(8)))  short bf16x8;
typedef __attribute__((ext_vector_type(4)))  float f32x4;
typedef __attribute__((ext_vector_type(16))) float f32x16;

__device__ __forceinline__ unsigned short f2bf(float f){
  union { float f; unsigned u; } v; v.f = f;
  unsigned r = v.u + 0x7FFFu + ((v.u >> 16) & 1u);
  return (unsigned short)(r >> 16);
}
__device__ __forceinline__ float bf2f(unsigned short u){
  union { unsigned u; float f; } v; v.u = ((unsigned)u) << 16;
  return v.f;
}
__device__ __forceinline__ unsigned pk2(float a, float b){
  return (unsigned)f2bf(a) | ((unsigned)f2bf(b) << 16);
}
__device__ __forceinline__ unsigned cvtpk(float a, float b){
  unsigned r;
  asm("v_cvt_pk_bf16_f32 %0, %1, %2" : "=v"(r) : "v"(a), "v"(b));
  return r;
}
__device__ __forceinline__ float exp2a(float x){   // bare v_exp_f32 (2^x)
  float r;
  asm("v_exp_f32 %0, %1" : "=v"(r) : "v"(x));
  return r;
}
__device__ __forceinline__ void gll16(const void* g, void* l){
  __builtin_amdgcn_global_load_lds(
      (const __attribute__((address_space(1))) unsigned int*)g,
      (__attribute__((address_space(3))) unsigned int*)l,
      16, 0, 0);
}

// ---------------- cast hidden_states fp32 -> bf16 ----------------
__global__ void k_cast_x(const float* __restrict__ x, unsigned short* __restrict__ xb){
  long i = ((long)blockIdx.x*256 + threadIdx.x)*4;
  float4 v = *(const float4*)(x + i);
  ushort4 o; o.x=f2bf(v.x); o.y=f2bf(v.y); o.z=f2bf(v.z); o.w=f2bf(v.w);
  *(ushort4*)(xb + i) = o;
}

// ---------------- transpose-cast 4 weights: W[k][n] fp32 -> Wt[n][k] bf16 ----------------
__global__ void k_wt4(const float* __restrict__ W0, const float* __restrict__ W1,
                      const float* __restrict__ W2, const float* __restrict__ W3,
                      unsigned short* __restrict__ T0, unsigned short* __restrict__ T1,
                      unsigned short* __restrict__ T2, unsigned short* __restrict__ T3){
  __shared__ float tile[64][65];
  const int z = blockIdx.z;
  const float* W = (z==0)? W0 : (z==1)? W1 : (z==2)? W2 : W3;
  unsigned short* Wt = (z==0)? T0 : (z==1)? T1 : (z==2)? T2 : T3;
  int kt = blockIdx.y*64, nt = blockIdx.x*64;
  int t = threadIdx.x;
  int r = t >> 4, c4 = (t & 15)*4;
#pragma unroll
  for (int i=0;i<4;i++){
    int k = r + i*16;
    float4 v = *(const float4*)(W + (size_t)(kt + k)*DM_ + nt + c4);
    tile[k][c4] = v.x; tile[k][c4+1]=v.y; tile[k][c4+2]=v.z; tile[k][c4+3]=v.w;
  }
  __syncthreads();
#pragma unroll
  for (int i=0;i<4;i++){
    int n = r + i*16;
    ushort4 o;
    o.x = f2bf(tile[c4+0][n]); o.y = f2bf(tile[c4+1][n]);
    o.z = f2bf(tile[c4+2][n]); o.w = f2bf(tile[c4+3][n]);
    *(ushort4*)(Wt + (size_t)(nt + n)*DM_ + kt + c4) = o;
  }
}

// ---------------- RoPE sin/cos table ----------------
__global__ void k_tab(float2* __restrict__ tab){
  int n = blockIdx.x*64 + threadIdx.x;
  int f = n >> 8, rem = n & 255, hh = rem >> 4, ww = rem & 15;
  float pos[3]; pos[0]=(float)f; pos[1]=(float)hh; pos[2]=(float)ww;
#pragma unroll
  for (int c=0;c<3;c++)
#pragma unroll
    for (int i=0;i<10;i++){
      float inv = exp2f(-(float)i * 1.3287712379549449f);  // 10000^(-i/10)
      float s, co;
      sincosf(pos[c]*inv, &s, &co);
      tab[n*30 + c*10 + i] = make_float2(co, s);
    }
}

// ---------------- 256x256 BK=64 counted-vmcnt GEMM (T2+T3+T4+T5) ----------------
// 512 threads (8 waves 2Mx4N), per-wave C 128x64, dbuf LDS 128KB.
// Stage: gll16 linear dest, pre-swizzled global source (chunk ^= row&7);
// reads swizzled byte ^= (row&7)<<4.  Loop: vmcnt(8); bar; ds_reads; MFMA half0;
// lgkm(0); bar; stage(kt+2); MFMA half1.  Never drains vmcnt in the loop.
// MODE 0: QKV fused (grid 384).  MODE 1: O-proj fp32 out (grid 128).
__device__ __forceinline__ void stage256(const unsigned short* __restrict__ gsrc,
                                         char* ldst, int tid){
  const int srow = tid >> 3;
  const int gch  = (tid & 7) ^ (srow & 7);
  const unsigned short* gp = gsrc + (size_t)srow*DM_ + gch*8;
  char* lp = ldst + tid*16;
#pragma unroll
  for (int j=0;j<4;j++)
    gll16(gp + (size_t)(j*64)*DM_, lp + j*8192);
}

template<int MODE>
__global__ __launch_bounds__(512, 2) void k_gemm256(
    const unsigned short* __restrict__ A,
    const unsigned short* __restrict__ w0,
    const unsigned short* __restrict__ w1,
    const unsigned short* __restrict__ w2,
    const float* __restrict__ b0,
    const float* __restrict__ b1,
    const float* __restrict__ b2,
    unsigned short* __restrict__ Qb,
    unsigned short* __restrict__ Kb,
    unsigned short* __restrict__ VTb,
    float* __restrict__ Fout)
{
  extern __shared__ char smem[];
  char* aL = smem;            // 2 x 32KB A tiles
  char* bL = smem + 65536;    // 2 x 32KB B tiles
  const int tid = threadIdx.x, lane = tid & 63, w = tid >> 6;
  const int qc = lane & 15, g = lane >> 4;
  const int wm = (w >> 2)*128, wn = (w & 3)*64;

  int mat, mt, nt;
  {
    int id = blockIdx.x;
    if (MODE == 0){
      int wg = (id & 7)*48 + (id >> 3);     // bijective XCD chunking (384%8==0)
      mat = wg >> 7; int rem = wg & 127;
      mt = (rem >> 2)*256; nt = (rem & 3)*256;
    } else {
      int wg = (id & 7)*16 + (id >> 3);     // 128%8==0
      mat = 0; mt = (wg >> 2)*256; nt = (wg & 3)*256;
    }
  }
  const unsigned short* Wt = (MODE==1)? w0 : ((mat==0)? w0 : (mat==1)? w1 : w2);
  const float* bias        = (MODE==1)? b0 : ((mat==0)? b0 : (mat==1)? b1 : b2);

  const unsigned short* Ab = A  + (size_t)mt*DM_;
  const unsigned short* Bb = Wt + (size_t)nt*DM_;

  // prologue: 2 tiles in flight (16 gll16)
  stage256(Ab,      aL,         tid);
  stage256(Bb,      bL,         tid);
  stage256(Ab + 64, aL + 32768, tid);
  stage256(Bb + 64, bL + 32768, tid);

  f32x4 acc[8][4] = {};

  for (int kt = 0; kt < 16; ++kt){
    const int bu = kt & 1;
    if (kt < 15) asm volatile("s_waitcnt vmcnt(8)" ::: "memory");
    else         asm volatile("s_waitcnt vmcnt(0)" ::: "memory");
    __builtin_amdgcn_s_barrier();
    __builtin_amdgcn_sched_barrier(0);
    const char* aT = aL + bu*32768;
    const char* bT = bL + bu*32768;

    bf16x8 bfr[4][2], af[4][2], af2[4][2];
#pragma unroll
    for (int n=0;n<4;n++)
#pragma unroll
      for (int ks=0;ks<2;ks++){
        int row = wn + n*16 + qc;
        bfr[n][ks] = *(const bf16x8*)(bT + row*128 + ((ks*64 + g*16) ^ ((row&7)<<4)));
      }
#pragma unroll
    for (int m=0;m<4;m++)
#pragma unroll
      for (int ks=0;ks<2;ks++){
        int row = wm + m*16 + qc;
        af[m][ks] = *(const bf16x8*)(aT + row*128 + ((ks*64 + g*16) ^ ((row&7)<<4)));
      }
    __builtin_amdgcn_s_setprio(1);
#pragma unroll
    for (int m=0;m<4;m++)
#pragma unroll
      for (int n=0;n<4;n++)
#pragma unroll
        for (int ks=0;ks<2;ks++)
          acc[m][n] = __builtin_amdgcn_mfma_f32_16x16x32_bf16(af[m][ks], bfr[n][ks], acc[m][n], 0,0,0);
    __builtin_amdgcn_s_setprio(0);
#pragma unroll
    for (int m=0;m<4;m++)
#pragma unroll
      for (int ks=0;ks<2;ks++){
        int row = wm + 64 + m*16 + qc;
        af2[m][ks] = *(const bf16x8*)(aT + row*128 + ((ks*64 + g*16) ^ ((row&7)<<4)));
      }
    asm volatile("s_waitcnt lgkmcnt(0)" ::: "memory");
    __builtin_amdgcn_sched_barrier(0);
    __builtin_amdgcn_s_barrier();
    __builtin_amdgcn_sched_barrier(0);
    if (kt < 14){
      stage256(Ab + (size_t)(kt+2)*64, aL + bu*32768, tid);
      stage256(Bb + (size_t)(kt+2)*64, bL + bu*32768, tid);
    }
    __builtin_amdgcn_s_setprio(1);
#pragma unroll
    for (int m=0;m<4;m++)
#pragma unroll
      for (int n=0;n<4;n++)
#pragma unroll
        for (int ks=0;ks<2;ks++)
          acc[4+m][n] = __builtin_amdgcn_mfma_f32_16x16x32_bf16(af2[m][ks], bfr[n][ks], acc[4+m][n], 0,0,0);
    __builtin_amdgcn_s_setprio(0);
  }

  if (MODE == 1){
#pragma unroll
    for (int n=0;n<4;n++){
      int col = nt + wn + n*16 + qc;
      float bv = bias[col];
#pragma unroll
      for (int m=0;m<8;m++){
#pragma unroll
        for (int r=0;r<4;r++){
          int mrow = mt + wm + m*16 + g*4 + r;
          Fout[(size_t)mrow*DM_ + col] = acc[m][n][r] + bv;
        }
      }
    }
  } else if (mat < 2){
    unsigned short* out = (mat==0)? Qb : Kb;
#pragma unroll
    for (int n=0;n<4;n++){
      int col = nt + wn + n*16 + qc;
      float bv = bias[col];
      int hh = col >> 6, d = col & 63;
#pragma unroll
      for (int m=0;m<8;m++){
#pragma unroll
        for (int r=0;r<4;r++){
          int mrow = mt + wm + m*16 + g*4 + r;
          size_t idx = (((size_t)(mrow >> 11)*H_ + hh)*NS_ + (mrow & (NS_-1)))*HD_ + d;
          out[idx] = f2bf(acc[m][n][r] + bv);
        }
      }
    }
  } else {
#pragma unroll
    for (int n=0;n<4;n++){
      int col = nt + wn + n*16 + qc;
      float bv = bias[col];
      int hh = col >> 6, d = col & 63;
#pragma unroll
      for (int m=0;m<8;m++){
        int mrow0 = mt + wm + m*16 + g*4;     // 4 consecutive tokens
        int b = mrow0 >> 11, ntk = mrow0 & (NS_-1);
        int pos = (ntk & ~12) | ((ntk & 4) << 1) | ((ntk & 8) >> 1);  // swap bits 2,3
        ushort4 o;
        o.x = f2bf(acc[m][n][0] + bv);
        o.y = f2bf(acc[m][n][1] + bv);
        o.z = f2bf(acc[m][n][2] + bv);
        o.w = f2bf(acc[m][n][3] + bv);
        *(ushort4*)(VTb + (((size_t)(b*H_ + hh)*HD_ + d)*NS_ + pos)) = o;
      }
    }
  }
}

// ---------------- in-place RoPE on Q,K; Q scaled by 0.125*log2(e) ----------------
#define QSCALE 0.18033688011112042f   // 0.125 * log2(e): softmax runs in log2 units
__global__ void k_rope(unsigned short* __restrict__ Qb, unsigned short* __restrict__ Kb,
                       const float2* __restrict__ tab)
{
  const int t = threadIdx.x;
  const int d4 = (t & 15)*4;
  const long gtok = (long)blockIdx.x*16 + (t >> 4);
  size_t base = (size_t)gtok*HD_ + d4;
  if (d4 >= 60){
    ushort4 v = *(ushort4*)(Qb + base);
    ushort4 o;
    o.x = f2bf(bf2f(v.x)*QSCALE); o.y = f2bf(bf2f(v.y)*QSCALE);
    o.z = f2bf(bf2f(v.z)*QSCALE); o.w = f2bf(bf2f(v.w)*QSCALE);
    *(ushort4*)(Qb + base) = o;
    return;
  }
  const int n = (int)(gtok & (NS_-1));
  const int c = d4 / 20;
  const int dd = d4 - c*20;
  const float2* tb = tab + n*30 + c*10;
  float2 cs0 = tb[(dd+0) % 10];
  float2 cs1 = tb[(dd+1) % 10];
  float2 cs2 = tb[(dd+2) % 10];
  float2 cs3 = tb[(dd+3) % 10];
#pragma unroll
  for (int which = 0; which < 2; which++){
    unsigned short* P = which ? Kb : Qb;
    float sc = which ? 1.f : QSCALE;
    ushort4 v = *(ushort4*)(P + base);
    float x0=bf2f(v.x), x1=bf2f(v.y), x2=bf2f(v.z), x3=bf2f(v.w);
    ushort4 o;
    o.x = f2bf((x0*cs0.x - x1*cs0.y)*sc);
    o.y = f2bf((x1*cs1.x + x0*cs1.y)*sc);
    o.z = f2bf((x2*cs2.x - x3*cs2.y)*sc);
    o.w = f2bf((x3*cs3.x + x2*cs3.y)*sc);
    *(ushort4*)(P + base) = o;
  }
}

// ---------------- 4-warp flash attention, 32x32 MFMA, swapped QK^T ----------------
__global__ __launch_bounds__(256, 4) void k_attn(const unsigned short* __restrict__ Q,
                                                 const unsigned short* __restrict__ K,
                                                 const unsigned short* __restrict__ VT,
                                                 unsigned short* __restrict__ ctxout)
{
  __shared__ __attribute__((aligned(16))) char smem[32768]; // 2 bufs x (8KB K + 8KB VT)
  const int tid  = threadIdx.x;
  const int lane = tid & 63, w = tid >> 6;       // w = 0..3
  const int qcol = lane & 31, h = lane >> 5;
  const int sw   = (lane & 7) << 4;
  const int bh   = blockIdx.x;
  const int q0   = blockIdx.y*128 + w*32;

  const unsigned short* Qp = Q  + ((size_t)bh*NS_ + q0)*HD_;
  const unsigned short* Kp = K  + (size_t)bh*NS_*HD_;
  const unsigned short* Vp = VT + (size_t)bh*HD_*NS_;

  const int trow = tid >> 3;                 // 0..31
  const int tc   = (tid & 7) ^ (trow & 7);

  bf16x8 qf[4];
#pragma unroll
  for (int i=0;i<4;i++)
    qf[i] = *(const bf16x8*)(Qp + (size_t)qcol*HD_ + 16*i + 8*h);

  {
    const unsigned short* gk = Kp + (size_t)trow*HD_ + tc*8;
    const unsigned short* gv = Vp + (size_t)trow*NS_ + tc*8;
    gll16(gk,          smem + w*1024);
    gll16(gk + 32*HD_, smem + 4096 + w*1024);
    gll16(gv,          smem + 8192 + w*1024);
    gll16(gv + 32*NS_, smem + 8192 + 4096 + w*1024);
  }

  f32x16 ctx0 = {}, ctx1 = {};
  float mrun = -1e30f, lp = 0.f;

  for (int t = 0; t < NS_/64; ++t){
    const int curo = (t & 1) * 16384;
    __syncthreads();
    if (t + 1 < NS_/64){
      const int kb = (t+1)*64;
      const int nxt = ((t+1) & 1) * 16384;
      const unsigned short* gk = Kp + (size_t)(kb + trow)*HD_ + tc*8;
      const unsigned short* gv = Vp + (size_t)trow*NS_ + kb + tc*8;
      gll16(gk,          smem + nxt + w*1024);
      gll16(gk + 32*HD_, smem + nxt + 4096 + w*1024);
      gll16(gv,          smem + nxt + 8192 + w*1024);
      gll16(gv + 32*NS_, smem + nxt + 8192 + 4096 + w*1024);
    }
    const char* kls = smem + curo;
    const char* vls = smem + curo + 8192;

#pragma unroll
    for (int s = 0; s < 2; ++s){
      f32x16 st = {};
      __builtin_amdgcn_s_setprio(1);
#pragma unroll
      for (int i=0;i<4;i++){
        bf16x8 kf = *(const bf16x8*)(kls + ((((32*s + qcol)*128) + 32*i + 16*h) ^ sw));
        st = __builtin_amdgcn_mfma_f32_32x32x16_bf16(kf, qf[i], st, 0,0,0);
      }
      __builtin_amdgcn_s_setprio(0);
      float a0 = fmaxf(fmaxf(st[0],  st[1]),  st[2]);
      float a1 = fmaxf(fmaxf(st[3],  st[4]),  st[5]);
      float a2 = fmaxf(fmaxf(st[6],  st[7]),  st[8]);
      float a3 = fmaxf(fmaxf(st[9],  st[10]), st[11]);
      float a4 = fmaxf(fmaxf(st[12], st[13]), st[14]);
      float tm = fmaxf(fmaxf(fmaxf(a0,a1),a2), fmaxf(fmaxf(a3,a4),st[15]));
      if (!__all(tm - mrun <= 11.5f)){
        float tp = fmaxf(tm, __shfl_xor(tm, 32));
        float mnew = fmaxf(mrun, tp);
        float alpha = exp2a(mrun - mnew);
        lp *= alpha;
#pragma unroll
        for (int r=0;r<16;r++){ ctx0[r]*=alpha; ctx1[r]*=alpha; }
        mrun = mnew;
      }
      unsigned u[8];
      float ps = 0.f;
#pragma unroll
      for (int r=0;r<8;r++){
        float ea = exp2a(st[2*r]   - mrun);
        float eb = exp2a(st[2*r+1] - mrun);
        unsigned uu = cvtpk(ea, eb);
        u[r] = uu;
        union { unsigned q; float f; } lo, hi;
        lo.q = uu << 16; hi.q = uu & 0xFFFF0000u;
        ps += lo.f + hi.f;
      }
      lp += ps;
      bf16x8 pf0 = __builtin_bit_cast(bf16x8, make_uint4(u[0],u[1],u[2],u[3]));
      bf16x8 pf1 = __builtin_bit_cast(bf16x8, make_uint4(u[4],u[5],u[6],u[7]));

      __builtin_amdgcn_s_setprio(1);
#pragma unroll
      for (int kc=0; kc<2; ++kc){
        const bf16x8 pf = kc ? pf1 : pf0;
        bf16x8 vf0 = *(const bf16x8*)(vls + ((qcol)*128      + ((64*s + 32*kc + 16*h) ^ sw)));
        ctx0 = __builtin_amdgcn_mfma_f32_32x32x16_bf16(vf0, pf, ctx0, 0,0,0);
        bf16x8 vf1 = *(const bf16x8*)(vls + ((32 + qcol)*128 + ((64*s + 32*kc + 16*h) ^ sw)));
        ctx1 = __builtin_amdgcn_mfma_f32_32x32x16_bf16(vf1, pf, ctx1, 0,0,0);
      }
      __builtin_amdgcn_s_setprio(0);
    }
  }

  float lsum = lp + __shfl_xor(lp, 32);
  float linv = 1.f / lsum;
  __syncthreads();
  char* reg = smem + w*4096;
#pragma unroll
  for (int rq=0; rq<4; ++rq){
    int db0 = 8*rq + 4*h;
    uint2 v0, v1;
    v0.x = pk2(ctx0[4*rq+0]*linv, ctx0[4*rq+1]*linv);
    v0.y = pk2(ctx0[4*rq+2]*linv, ctx0[4*rq+3]*linv);
    v1.x = pk2(ctx1[4*rq+0]*linv, ctx1[4*rq+1]*linv);
    v1.y = pk2(ctx1[4*rq+2]*linv, ctx1[4*rq+3]*linv);
    *(uint2*)(reg + qcol*128 + db0*2)      = v0;
    *(uint2*)(reg + qcol*128 + (32+db0)*2) = v1;
  }
  __syncthreads();
  const int b = bh >> 4, head = bh & 15;
  unsigned short* outp = ctxout + ((size_t)b*NS_ + q0)*DM_ + head*HD_;
#pragma unroll
  for (int p=0;p<4;p++){
    int row = p*8 + (lane>>3);
    uint4 v = *(const uint4*)(reg + row*128 + (lane&7)*16);
    *(uint4*)(outp + (size_t)row*DM_ + (lane&7)*8) = v;
  }
}

extern "C" void kernel_launch(void* const* d_in, const int* in_sizes, int n_in,
                              void* d_out, int out_size, void* d_ws, size_t ws_size,
                              hipStream_t stream)
{
  const float* hs = (const float*)d_in[0];
  const float* Wq = (const float*)d_in[1];
  const float* bq = (const float*)d_in[2];
  const float* Wk = (const float*)d_in[3];
  const float* bk = (const float*)d_in[4];
  const float* Wv = (const float*)d_in[5];
  const float* bv = (const float*)d_in[6];
  const float* Wo = (const float*)d_in[7];
  const float* bo = (const float*)d_in[8];

  char* ws = (char*)d_ws;
  size_t off = 0;
  auto alloc = [&](size_t b){ void* p = ws + off; off += (b + 255) & ~(size_t)255; return p; };
  unsigned short* xb  = (unsigned short*)alloc((size_t)MTOT*DM_*2);
  unsigned short* wqt = (unsigned short*)alloc((size_t)DM_*DM_*2);
  unsigned short* wkt = (unsigned short*)alloc((size_t)DM_*DM_*2);
  unsigned short* wvt = (unsigned short*)alloc((size_t)DM_*DM_*2);
  unsigned short* wot = (unsigned short*)alloc((size_t)DM_*DM_*2);
  float2*         tab = (float2*)alloc((size_t)NS_*30*sizeof(float2));
  unsigned short* Qb  = (unsigned short*)alloc((size_t)MTOT*DM_*2);
  unsigned short* Kb  = (unsigned short*)alloc((size_t)MTOT*DM_*2);
  unsigned short* VTb = (unsigned short*)alloc((size_t)MTOT*DM_*2);
  unsigned short* cxb = (unsigned short*)alloc((size_t)MTOT*DM_*2);

  // allow 128KB dynamic LDS for the 256^2 GEMM (no-op if already set)
  hipFuncSetAttribute((const void*)k_gemm256<0>,
                      hipFuncAttributeMaxDynamicSharedMemorySize, 131072);
  hipFuncSetAttribute((const void*)k_gemm256<1>,
                      hipFuncAttributeMaxDynamicSharedMemorySize, 131072);

  k_cast_x<<<dim3(MTOT*DM_/1024), dim3(256), 0, stream>>>(hs, xb);
  k_wt4<<<dim3(16,16,4), dim3(256), 0, stream>>>(Wq, Wk, Wv, Wo, wqt, wkt, wvt, wot);
  k_tab<<<dim3(32), dim3(64), 0, stream>>>(tab);

  k_gemm256<0><<<dim3(384), dim3(512), 131072, stream>>>(
      xb, wqt, wkt, wvt, bq, bk, bv, Qb, Kb, VTb, (float*)nullptr);

  k_rope<<<dim3(64*NS_/16), dim3(256), 0, stream>>>(Qb, Kb, tab);

  k_attn<<<dim3(64, 16), dim3(256), 0, stream>>>(Qb, Kb, VTb, cxb);

  k_gemm256<1><<<dim3(128), dim3(512), 131072, stream>>>(
      cxb, wot, nullptr, nullptr, bo, nullptr, nullptr,
      nullptr, nullptr, nullptr, (float*)d_out);
}

// Round 9
// 235.474 us; speedup vs baseline: 1.2724x; 1.0192x over previous
//
#include <hip/hip_runtime.h>
#include <stdint.h>

#define H_   16
#define NS_  2048
#define B_   4
#define DM_  1024
#define HD_  64
#define MTOT (B_*NS_)   // 8192 tokens

typedef __attribute__((ext_vector_type(8)))  short bf16x8;
typedef __attribute__((ext_vector_type(4)))  float f32x4;
typedef __attribute__((ext_vector_type(16))) float f32x16;

__device__ __forceinline__ unsigned short f2bf(float f){
  union { float f; unsigned u; } v; v.f = f;
  unsigned r = v.u + 0x7FFFu + ((v.u >> 16) & 1u);
  return (unsigned short)(r >> 16);
}
__device__ __forceinline__ float bf2f(unsigned short u){
  union { unsigned u; float f; } v; v.u = ((unsigned)u) << 16;
  return v.f;
}
__device__ __forceinline__ unsigned pk2(float a, float b){
  return (unsigned)f2bf(a) | ((unsigned)f2bf(b) << 16);
}
__device__ __forceinline__ unsigned cvtpk(float a, float b){
  unsigned r;
  asm("v_cvt_pk_bf16_f32 %0, %1, %2" : "=v"(r) : "v"(a), "v"(b));
  return r;
}
__device__ __forceinline__ float exp2a(float x){   // bare v_exp_f32 (2^x)
  float r;
  asm("v_exp_f32 %0, %1" : "=v"(r) : "v"(x));
  return r;
}
__device__ __forceinline__ void gll16(const void* g, void* l){
  __builtin_amdgcn_global_load_lds(
      (const __attribute__((address_space(1))) unsigned int*)g,
      (__attribute__((address_space(3))) unsigned int*)l,
      16, 0, 0);
}

// ---------------- fused prep: cast x, transpose-cast 4 weights, rope table ----------------
__global__ void k_prep(const float* __restrict__ hs, unsigned short* __restrict__ xb,
                       const float* __restrict__ W0, const float* __restrict__ W1,
                       const float* __restrict__ W2, const float* __restrict__ W3,
                       unsigned short* __restrict__ T0, unsigned short* __restrict__ T1,
                       unsigned short* __restrict__ T2, unsigned short* __restrict__ T3,
                       float2* __restrict__ tab)
{
  __shared__ float tile[64][65];
  const int bid = blockIdx.x, t = threadIdx.x;
  if (bid < 8192){
    long i = ((long)bid*256 + t)*4;
    float4 v = *(const float4*)(hs + i);
    ushort4 o; o.x=f2bf(v.x); o.y=f2bf(v.y); o.z=f2bf(v.z); o.w=f2bf(v.w);
    *(ushort4*)(xb + i) = o;
    return;
  }
  if (bid < 9216){
    int id = bid - 8192;
    const int z = id >> 8; id &= 255;
    const float* W = (z==0)? W0 : (z==1)? W1 : (z==2)? W2 : W3;
    unsigned short* Wt = (z==0)? T0 : (z==1)? T1 : (z==2)? T2 : T3;
    int kt = (id >> 4)*64, nt = (id & 15)*64;
    int r = t >> 4, c4 = (t & 15)*4;
#pragma unroll
    for (int i=0;i<4;i++){
      int k = r + i*16;
      float4 v = *(const float4*)(W + (size_t)(kt + k)*DM_ + nt + c4);
      tile[k][c4] = v.x; tile[k][c4+1]=v.y; tile[k][c4+2]=v.z; tile[k][c4+3]=v.w;
    }
    __syncthreads();
#pragma unroll
    for (int i=0;i<4;i++){
      int n = r + i*16;
      ushort4 o;
      o.x = f2bf(tile[c4+0][n]); o.y = f2bf(tile[c4+1][n]);
      o.z = f2bf(tile[c4+2][n]); o.w = f2bf(tile[c4+3][n]);
      *(ushort4*)(Wt + (size_t)(nt + n)*DM_ + kt + c4) = o;
    }
    return;
  }
  {
    int n = (bid - 9216)*256 + t;          // 8 blocks x 256 = 2048
    int f = n >> 8, rem = n & 255, hh = rem >> 4, ww = rem & 15;
    float pos[3]; pos[0]=(float)f; pos[1]=(float)hh; pos[2]=(float)ww;
#pragma unroll
    for (int c=0;c<3;c++)
#pragma unroll
      for (int i=0;i<10;i++){
        float inv = exp2f(-(float)i * 1.3287712379549449f);  // 10000^(-i/10)
        float s, co;
        sincosf(pos[c]*inv, &s, &co);
        tab[n*30 + c*10 + i] = make_float2(co, s);
      }
  }
}

// ---------------- 256x256 BK=64 counted-vmcnt GEMM (T2+T3+T4+T5) ----------------
// MODE 0: QKV fused.  Q,K -> token-major [8192][1024] bf16 (coalesced stores).
//         V -> VT_perm (B,H,64,N) bf16, sigma-permuted keys (bits 2<->3).
// MODE 1: O-proj fp32 out.
__device__ __forceinline__ void stage256(const unsigned short* __restrict__ gsrc,
                                         char* ldst, int tid){
  const int srow = tid >> 3;
  const int gch  = (tid & 7) ^ (srow & 7);
  const unsigned short* gp = gsrc + (size_t)srow*DM_ + gch*8;
  char* lp = ldst + tid*16;
#pragma unroll
  for (int j=0;j<4;j++)
    gll16(gp + (size_t)(j*64)*DM_, lp + j*8192);
}

template<int MODE>
__global__ __launch_bounds__(512, 2) void k_gemm256(
    const unsigned short* __restrict__ A,
    const unsigned short* __restrict__ w0,
    const unsigned short* __restrict__ w1,
    const unsigned short* __restrict__ w2,
    const float* __restrict__ b0,
    const float* __restrict__ b1,
    const float* __restrict__ b2,
    unsigned short* __restrict__ Qb,
    unsigned short* __restrict__ Kb,
    unsigned short* __restrict__ VTb,
    float* __restrict__ Fout)
{
  extern __shared__ char smem[];
  char* aL = smem;            // 2 x 32KB A tiles
  char* bL = smem + 65536;    // 2 x 32KB B tiles
  const int tid = threadIdx.x, lane = tid & 63, w = tid >> 6;
  const int qc = lane & 15, g = lane >> 4;
  const int wm = (w >> 2)*128, wn = (w & 3)*64;

  int mat, mt, nt;
  {
    int id = blockIdx.x;
    if (MODE == 0){
      int wg = (id & 7)*48 + (id >> 3);     // bijective XCD chunking (384%8==0)
      mat = wg >> 7; int rem = wg & 127;
      mt = (rem >> 2)*256; nt = (rem & 3)*256;
    } else {
      int wg = (id & 7)*16 + (id >> 3);     // 128%8==0
      mat = 0; mt = (wg >> 2)*256; nt = (wg & 3)*256;
    }
  }
  const unsigned short* Wt = (MODE==1)? w0 : ((mat==0)? w0 : (mat==1)? w1 : w2);
  const float* bias        = (MODE==1)? b0 : ((mat==0)? b0 : (mat==1)? b1 : b2);

  const unsigned short* Ab = A  + (size_t)mt*DM_;
  const unsigned short* Bb = Wt + (size_t)nt*DM_;

  stage256(Ab,      aL,         tid);
  stage256(Bb,      bL,         tid);
  stage256(Ab + 64, aL + 32768, tid);
  stage256(Bb + 64, bL + 32768, tid);

  f32x4 acc[8][4] = {};

  for (int kt = 0; kt < 16; ++kt){
    const int bu = kt & 1;
    if (kt < 15) asm volatile("s_waitcnt vmcnt(8)" ::: "memory");
    else         asm volatile("s_waitcnt vmcnt(0)" ::: "memory");
    __builtin_amdgcn_s_barrier();
    __builtin_amdgcn_sched_barrier(0);
    const char* aT = aL + bu*32768;
    const char* bT = bL + bu*32768;

    bf16x8 bfr[4][2], af[4][2], af2[4][2];
#pragma unroll
    for (int n=0;n<4;n++)
#pragma unroll
      for (int ks=0;ks<2;ks++){
        int row = wn + n*16 + qc;
        bfr[n][ks] = *(const bf16x8*)(bT + row*128 + ((ks*64 + g*16) ^ ((row&7)<<4)));
      }
#pragma unroll
    for (int m=0;m<4;m++)
#pragma unroll
      for (int ks=0;ks<2;ks++){
        int row = wm + m*16 + qc;
        af[m][ks] = *(const bf16x8*)(aT + row*128 + ((ks*64 + g*16) ^ ((row&7)<<4)));
      }
    __builtin_amdgcn_s_setprio(1);
#pragma unroll
    for (int m=0;m<4;m++)
#pragma unroll
      for (int n=0;n<4;n++)
#pragma unroll
        for (int ks=0;ks<2;ks++)
          acc[m][n] = __builtin_amdgcn_mfma_f32_16x16x32_bf16(af[m][ks], bfr[n][ks], acc[m][n], 0,0,0);
    __builtin_amdgcn_s_setprio(0);
#pragma unroll
    for (int m=0;m<4;m++)
#pragma unroll
      for (int ks=0;ks<2;ks++){
        int row = wm + 64 + m*16 + qc;
        af2[m][ks] = *(const bf16x8*)(aT + row*128 + ((ks*64 + g*16) ^ ((row&7)<<4)));
      }
    asm volatile("s_waitcnt lgkmcnt(0)" ::: "memory");
    __builtin_amdgcn_sched_barrier(0);
    __builtin_amdgcn_s_barrier();
    __builtin_amdgcn_sched_barrier(0);
    if (kt < 14){
      stage256(Ab + (size_t)(kt+2)*64, aL + bu*32768, tid);
      stage256(Bb + (size_t)(kt+2)*64, bL + bu*32768, tid);
    }
    __builtin_amdgcn_s_setprio(1);
#pragma unroll
    for (int m=0;m<4;m++)
#pragma unroll
      for (int n=0;n<4;n++)
#pragma unroll
        for (int ks=0;ks<2;ks++)
          acc[4+m][n] = __builtin_amdgcn_mfma_f32_16x16x32_bf16(af2[m][ks], bfr[n][ks], acc[4+m][n], 0,0,0);
    __builtin_amdgcn_s_setprio(0);
  }

  if (MODE == 1){
#pragma unroll
    for (int n=0;n<4;n++){
      int col = nt + wn + n*16 + qc;
      float bv = bias[col];
#pragma unroll
      for (int m=0;m<8;m++){
#pragma unroll
        for (int r=0;r<4;r++){
          int mrow = mt + wm + m*16 + g*4 + r;
          Fout[(size_t)mrow*DM_ + col] = acc[m][n][r] + bv;
        }
      }
    }
  } else if (mat < 2){
    // token-major [8192][1024]: adjacent lanes -> adjacent cols (coalesced)
    unsigned short* out = (mat==0)? Qb : Kb;
#pragma unroll
    for (int n=0;n<4;n++){
      int col = nt + wn + n*16 + qc;
      float bv = bias[col];
#pragma unroll
      for (int m=0;m<8;m++){
#pragma unroll
        for (int r=0;r<4;r++){
          int mrow = mt + wm + m*16 + g*4 + r;
          out[(size_t)mrow*DM_ + col] = f2bf(acc[m][n][r] + bv);
        }
      }
    }
  } else {
#pragma unroll
    for (int n=0;n<4;n++){
      int col = nt + wn + n*16 + qc;
      float bv = bias[col];
      int hh = col >> 6, d = col & 63;
#pragma unroll
      for (int m=0;m<8;m++){
        int mrow0 = mt + wm + m*16 + g*4;     // 4 consecutive tokens
        int b = mrow0 >> 11, ntk = mrow0 & (NS_-1);
        int pos = (ntk & ~12) | ((ntk & 4) << 1) | ((ntk & 8) >> 1);  // swap bits 2,3
        ushort4 o;
        o.x = f2bf(acc[m][n][0] + bv);
        o.y = f2bf(acc[m][n][1] + bv);
        o.z = f2bf(acc[m][n][2] + bv);
        o.w = f2bf(acc[m][n][3] + bv);
        *(ushort4*)(VTb + (((size_t)(b*H_ + hh)*HD_ + d)*NS_ + pos)) = o;
      }
    }
  }
}

// ---------------- flat RoPE on token-major Q,K; Q scaled by 0.125*log2(e) ----------------
#define QSCALE 0.18033688011112042f   // 0.125 * log2(e): softmax runs in log2 units
__global__ void k_rope(unsigned short* __restrict__ Qb, unsigned short* __restrict__ Kb,
                       const float2* __restrict__ tab)
{
  const int t = threadIdx.x;
  const long token = (long)blockIdx.x*2 + (t >> 7);
  const int fd = (t & 127)*8;                // flat dim, 8 per thread, same head
  const int n = (int)(token & (NS_-1));
  const int d = fd & 63;
  const float2* tb = tab + n*30;
  float2 cs[8];
#pragma unroll
  for (int j=0;j<8;j++){
    int e = d + j;
    if (e < 60){
      int c = e/20; int rr = e - 20*c; if (rr >= 10) rr -= 10;
      cs[j] = tb[c*10 + rr];                 // per-ELEMENT freq (tile, not interleave)
    } else cs[j] = make_float2(1.f, 0.f);    // pass-through as rotation by 0
  }
  size_t base = (size_t)token*DM_ + fd;
#pragma unroll
  for (int which = 0; which < 2; which++){
    unsigned short* P = which ? Kb : Qb;
    float sc = which ? 1.f : QSCALE;
    ushort4 va = *(ushort4*)(P + base);
    ushort4 vb = *(ushort4*)(P + base + 4);
    float x[8] = {bf2f(va.x),bf2f(va.y),bf2f(va.z),bf2f(va.w),
                  bf2f(vb.x),bf2f(vb.y),bf2f(vb.z),bf2f(vb.w)};
    unsigned short o[8];
#pragma unroll
    for (int j=0;j<8;j+=2){
      o[j]   = f2bf((x[j]*cs[j].x     - x[j+1]*cs[j].y)  *sc);
      o[j+1] = f2bf((x[j+1]*cs[j+1].x + x[j]*cs[j+1].y)  *sc);
    }
    ushort4 oa = {o[0],o[1],o[2],o[3]}, ob = {o[4],o[5],o[6],o[7]};
    *(ushort4*)(P + base)     = oa;
    *(ushort4*)(P + base + 4) = ob;
  }
}

// ---------------- 4-warp flash attention, 32x32 MFMA, swapped QK^T ----------------
// Q,K token-major [8192][1024]. grid (bh=64, qblk=16), 4 blocks/CU.
// QK for BOTH 32-key subtiles hoisted before softmax (ILP: SM(s0) VALU chain
// overlaps QK(s1) MFMAs). Softmax log2-domain, defer-max, lane-local P.
__global__ __launch_bounds__(256, 4) void k_attn(const unsigned short* __restrict__ Q,
                                                 const unsigned short* __restrict__ K,
                                                 const unsigned short* __restrict__ VT,
                                                 unsigned short* __restrict__ ctxout)
{
  __shared__ __attribute__((aligned(16))) char smem[32768]; // 2 bufs x (8KB K + 8KB VT)
  const int tid  = threadIdx.x;
  const int lane = tid & 63, w = tid >> 6;       // w = 0..3
  const int qcol = lane & 31, h = lane >> 5;
  const int sw   = (lane & 7) << 4;
  const int bh   = blockIdx.x;
  const int b    = bh >> 4, head = bh & 15;
  const int q0   = blockIdx.y*128 + w*32;

  const unsigned short* Qp = Q  + ((size_t)(b*NS_ + q0))*DM_ + head*HD_;
  const unsigned short* Kp = K  + ((size_t)(b*NS_))*DM_ + head*HD_;
  const unsigned short* Vp = VT + (size_t)bh*HD_*NS_;

  const int trow = tid >> 3;                 // 0..31
  const int tc   = (tid & 7) ^ (trow & 7);

  bf16x8 qf[4];
#pragma unroll
  for (int i=0;i<4;i++)
    qf[i] = *(const bf16x8*)(Qp + (size_t)qcol*DM_ + 16*i + 8*h);

  {
    const unsigned short* gk = Kp + (size_t)trow*DM_ + tc*8;
    const unsigned short* gv = Vp + (size_t)trow*NS_ + tc*8;
    gll16(gk,          smem + w*1024);
    gll16(gk + 32*DM_, smem + 4096 + w*1024);
    gll16(gv,          smem + 8192 + w*1024);
    gll16(gv + 32*NS_, smem + 8192 + 4096 + w*1024);
  }

  f32x16 ctx0 = {}, ctx1 = {};
  float mrun = -1e30f, lp = 0.f;

  for (int t = 0; t < NS_/64; ++t){
    const int curo = (t & 1) * 16384;
    __syncthreads();
    if (t + 1 < NS_/64){
      const int kb = (t+1)*64;
      const int nxt = ((t+1) & 1) * 16384;
      const unsigned short* gk = Kp + (size_t)(kb + trow)*DM_ + tc*8;
      const unsigned short* gv = Vp + (size_t)trow*NS_ + kb + tc*8;
      gll16(gk,          smem + nxt + w*1024);
      gll16(gk + 32*DM_, smem + nxt + 4096 + w*1024);
      gll16(gv,          smem + nxt + 8192 + w*1024);
      gll16(gv + 32*NS_, smem + nxt + 8192 + 4096 + w*1024);
    }
    const char* kls = smem + curo;
    const char* vls = smem + curo + 8192;

    // ---- hoisted QK^T for both subtiles ----
    f32x16 st0 = {}, st1 = {};
    __builtin_amdgcn_s_setprio(1);
#pragma unroll
    for (int i=0;i<4;i++){
      bf16x8 kf = *(const bf16x8*)(kls + (((qcol)*128 + 32*i + 16*h) ^ sw));
      st0 = __builtin_amdgcn_mfma_f32_32x32x16_bf16(kf, qf[i], st0, 0,0,0);
    }
#pragma unroll
    for (int i=0;i<4;i++){
      bf16x8 kf = *(const bf16x8*)(kls + ((((32 + qcol)*128) + 32*i + 16*h) ^ sw));
      st1 = __builtin_amdgcn_mfma_f32_32x32x16_bf16(kf, qf[i], st1, 0,0,0);
    }
    __builtin_amdgcn_s_setprio(0);

#pragma unroll
    for (int s = 0; s < 2; ++s){
      f32x16& st = s ? st1 : st0;
      float a0 = fmaxf(fmaxf(st[0],  st[1]),  st[2]);
      float a1 = fmaxf(fmaxf(st[3],  st[4]),  st[5]);
      float a2 = fmaxf(fmaxf(st[6],  st[7]),  st[8]);
      float a3 = fmaxf(fmaxf(st[9],  st[10]), st[11]);
      float a4 = fmaxf(fmaxf(st[12], st[13]), st[14]);
      float tm = fmaxf(fmaxf(fmaxf(a0,a1),a2), fmaxf(fmaxf(a3,a4),st[15]));
      if (!__all(tm - mrun <= 11.5f)){
        float tp = fmaxf(tm, __shfl_xor(tm, 32));
        float mnew = fmaxf(mrun, tp);
        float alpha = exp2a(mrun - mnew);
        lp *= alpha;
#pragma unroll
        for (int r=0;r<16;r++){ ctx0[r]*=alpha; ctx1[r]*=alpha; }
        mrun = mnew;
      }
      unsigned u[8];
      float ps = 0.f;
#pragma unroll
      for (int r=0;r<8;r++){
        float ea = exp2a(st[2*r]   - mrun);
        float eb = exp2a(st[2*r+1] - mrun);
        unsigned uu = cvtpk(ea, eb);
        u[r] = uu;
        union { unsigned q; float f; } lo, hi;
        lo.q = uu << 16; hi.q = uu & 0xFFFF0000u;
        ps += lo.f + hi.f;
      }
      lp += ps;
      bf16x8 pf0 = __builtin_bit_cast(bf16x8, make_uint4(u[0],u[1],u[2],u[3]));
      bf16x8 pf1 = __builtin_bit_cast(bf16x8, make_uint4(u[4],u[5],u[6],u[7]));

      __builtin_amdgcn_s_setprio(1);
#pragma unroll
      for (int kc=0; kc<2; ++kc){
        const bf16x8 pf = kc ? pf1 : pf0;
        bf16x8 vf0 = *(const bf16x8*)(vls + ((qcol)*128      + ((64*s + 32*kc + 16*h) ^ sw)));
        ctx0 = __builtin_amdgcn_mfma_f32_32x32x16_bf16(vf0, pf, ctx0, 0,0,0);
        bf16x8 vf1 = *(const bf16x8*)(vls + ((32 + qcol)*128 + ((64*s + 32*kc + 16*h) ^ sw)));
        ctx1 = __builtin_amdgcn_mfma_f32_32x32x16_bf16(vf1, pf, ctx1, 0,0,0);
      }
      __builtin_amdgcn_s_setprio(0);
    }
  }

  float lsum = lp + __shfl_xor(lp, 32);
  float linv = 1.f / lsum;
  __syncthreads();
  char* reg = smem + w*4096;
#pragma unroll
  for (int rq=0; rq<4; ++rq){
    int db0 = 8*rq + 4*h;
    uint2 v0, v1;
    v0.x = pk2(ctx0[4*rq+0]*linv, ctx0[4*rq+1]*linv);
    v0.y = pk2(ctx0[4*rq+2]*linv, ctx0[4*rq+3]*linv);
    v1.x = pk2(ctx1[4*rq+0]*linv, ctx1[4*rq+1]*linv);
    v1.y = pk2(ctx1[4*rq+2]*linv, ctx1[4*rq+3]*linv);
    *(uint2*)(reg + qcol*128 + db0*2)      = v0;
    *(uint2*)(reg + qcol*128 + (32+db0)*2) = v1;
  }
  __syncthreads();
  unsigned short* outp = ctxout + ((size_t)(b*NS_ + q0))*DM_ + head*HD_;
#pragma unroll
  for (int p=0;p<4;p++){
    int row = p*8 + (lane>>3);
    uint4 v = *(const uint4*)(reg + row*128 + (lane&7)*16);
    *(uint4*)(outp + (size_t)row*DM_ + (lane&7)*8) = v;
  }
}

extern "C" void kernel_launch(void* const* d_in, const int* in_sizes, int n_in,
                              void* d_out, int out_size, void* d_ws, size_t ws_size,
                              hipStream_t stream)
{
  const float* hs = (const float*)d_in[0];
  const float* Wq = (const float*)d_in[1];
  const float* bq = (const float*)d_in[2];
  const float* Wk = (const float*)d_in[3];
  const float* bk = (const float*)d_in[4];
  const float* Wv = (const float*)d_in[5];
  const float* bv = (const float*)d_in[6];
  const float* Wo = (const float*)d_in[7];
  const float* bo = (const float*)d_in[8];

  char* ws = (char*)d_ws;
  size_t off = 0;
  auto alloc = [&](size_t b){ void* p = ws + off; off += (b + 255) & ~(size_t)255; return p; };
  unsigned short* xb  = (unsigned short*)alloc((size_t)MTOT*DM_*2);
  unsigned short* wqt = (unsigned short*)alloc((size_t)DM_*DM_*2);
  unsigned short* wkt = (unsigned short*)alloc((size_t)DM_*DM_*2);
  unsigned short* wvt = (unsigned short*)alloc((size_t)DM_*DM_*2);
  unsigned short* wot = (unsigned short*)alloc((size_t)DM_*DM_*2);
  float2*         tab = (float2*)alloc((size_t)NS_*30*sizeof(float2));
  unsigned short* Qb  = (unsigned short*)alloc((size_t)MTOT*DM_*2);
  unsigned short* Kb  = (unsigned short*)alloc((size_t)MTOT*DM_*2);
  unsigned short* VTb = (unsigned short*)alloc((size_t)MTOT*DM_*2);
  unsigned short* cxb = (unsigned short*)alloc((size_t)MTOT*DM_*2);

  hipFuncSetAttribute((const void*)k_gemm256<0>,
                      hipFuncAttributeMaxDynamicSharedMemorySize, 131072);
  hipFuncSetAttribute((const void*)k_gemm256<1>,
                      hipFuncAttributeMaxDynamicSharedMemorySize, 131072);

  k_prep<<<dim3(9224), dim3(256), 0, stream>>>(hs, xb, Wq, Wk, Wv, Wo,
                                               wqt, wkt, wvt, wot, tab);

  k_gemm256<0><<<dim3(384), dim3(512), 131072, stream>>>(
      xb, wqt, wkt, wvt, bq, bk, bv, Qb, Kb, VTb, (float*)nullptr);

  k_rope<<<dim3(MTOT/2), dim3(256), 0, stream>>>(Qb, Kb, tab);

  k_attn<<<dim3(64, 16), dim3(256), 0, stream>>>(Qb, Kb, VTb, cxb);

  k_gemm256<1><<<dim3(128), dim3(512), 131072, stream>>>(
      cxb, wot, nullptr, nullptr, bo, nullptr, nullptr,
      nullptr, nullptr, nullptr, (float*)d_out);
}

// Round 10
// 219.368 us; speedup vs baseline: 1.3658x; 1.0734x over previous
//
#include <hip/hip_runtime.h>
#include <stdint.h>

#define H_   16
#define NS_  2048
#define B_   4
#define DM_  1024
#define HD_  64
#define MTOT (B_*NS_)   // 8192 tokens

typedef __attribute__((ext_vector_type(8)))  short bf16x8;
typedef __attribute__((ext_vector_type(4)))  float f32x4;
typedef __attribute__((ext_vector_type(16))) float f32x16;

__device__ __forceinline__ unsigned short f2bf(float f){
  union { float f; unsigned u; } v; v.f = f;
  unsigned r = v.u + 0x7FFFu + ((v.u >> 16) & 1u);
  return (unsigned short)(r >> 16);
}
__device__ __forceinline__ float bf2f(unsigned short u){
  union { unsigned u; float f; } v; v.u = ((unsigned)u) << 16;
  return v.f;
}
__device__ __forceinline__ unsigned pk2(float a, float b){
  return (unsigned)f2bf(a) | ((unsigned)f2bf(b) << 16);
}
__device__ __forceinline__ unsigned cvtpk(float a, float b){
  unsigned r;
  asm("v_cvt_pk_bf16_f32 %0, %1, %2" : "=v"(r) : "v"(a), "v"(b));
  return r;
}
__device__ __forceinline__ float exp2a(float x){   // bare v_exp_f32 (2^x)
  float r;
  asm("v_exp_f32 %0, %1" : "=v"(r) : "v"(x));
  return r;
}
__device__ __forceinline__ void gll16(const void* g, void* l){
  __builtin_amdgcn_global_load_lds(
      (const __attribute__((address_space(1))) unsigned int*)g,
      (__attribute__((address_space(3))) unsigned int*)l,
      16, 0, 0);
}

// ---------------- fused prep: cast x, transpose-cast 4 weights, rope table ----------------
__global__ void k_prep(const float* __restrict__ hs, unsigned short* __restrict__ xb,
                       const float* __restrict__ W0, const float* __restrict__ W1,
                       const float* __restrict__ W2, const float* __restrict__ W3,
                       unsigned short* __restrict__ T0, unsigned short* __restrict__ T1,
                       unsigned short* __restrict__ T2, unsigned short* __restrict__ T3,
                       float2* __restrict__ tab)
{
  __shared__ float tile[64][65];
  const int bid = blockIdx.x, t = threadIdx.x;
  if (bid < 8192){
    long i = ((long)bid*256 + t)*4;
    float4 v = *(const float4*)(hs + i);
    ushort4 o; o.x=f2bf(v.x); o.y=f2bf(v.y); o.z=f2bf(v.z); o.w=f2bf(v.w);
    *(ushort4*)(xb + i) = o;
    return;
  }
  if (bid < 9216){
    int id = bid - 8192;
    const int z = id >> 8; id &= 255;
    const float* W = (z==0)? W0 : (z==1)? W1 : (z==2)? W2 : W3;
    unsigned short* Wt = (z==0)? T0 : (z==1)? T1 : (z==2)? T2 : T3;
    int kt = (id >> 4)*64, nt = (id & 15)*64;
    int r = t >> 4, c4 = (t & 15)*4;
#pragma unroll
    for (int i=0;i<4;i++){
      int k = r + i*16;
      float4 v = *(const float4*)(W + (size_t)(kt + k)*DM_ + nt + c4);
      tile[k][c4] = v.x; tile[k][c4+1]=v.y; tile[k][c4+2]=v.z; tile[k][c4+3]=v.w;
    }
    __syncthreads();
#pragma unroll
    for (int i=0;i<4;i++){
      int n = r + i*16;
      ushort4 o;
      o.x = f2bf(tile[c4+0][n]); o.y = f2bf(tile[c4+1][n]);
      o.z = f2bf(tile[c4+2][n]); o.w = f2bf(tile[c4+3][n]);
      *(ushort4*)(Wt + (size_t)(nt + n)*DM_ + kt + c4) = o;
    }
    return;
  }
  {
    int n = (bid - 9216)*256 + t;          // 8 blocks x 256 = 2048
    int f = n >> 8, rem = n & 255, hh = rem >> 4, ww = rem & 15;
    float pos[3]; pos[0]=(float)f; pos[1]=(float)hh; pos[2]=(float)ww;
#pragma unroll
    for (int c=0;c<3;c++)
#pragma unroll
      for (int i=0;i<10;i++){
        float inv = exp2f(-(float)i * 1.3287712379549449f);  // 10000^(-i/10)
        float s, co;
        sincosf(pos[c]*inv, &s, &co);
        tab[n*30 + c*10 + i] = make_float2(co, s);
      }
  }
}

// ---------------- 256x128 BK=64 counted-vmcnt GEMM (T2+T3+T4+T5) ----------------
// 512 threads = 8 waves (4M x 2N), per-wave C 64x64 (acc[4][4]).
// LDS 96KB: A dbuf 2x32KB, B dbuf 2x16KB.  vmcnt(6) steady state (4 A + 2 B
// gll16/thread per stage).  Grids sized to exact multiples of 256 CUs:
// MODE 0 (QKV fused): 3 x 32 x 8 = 768 blocks.  Q,K token-major [8192][1024];
//   V -> VT_perm (B,H,64,N), sigma-permuted keys (bits 2<->3).
// MODE 1 (O-proj fp32): 32 x 8 = 256 blocks.
__device__ __forceinline__ void stageA(const unsigned short* __restrict__ gsrc,
                                       char* ldst, int tid){
  const int srow = tid >> 3;
  const int gch  = (tid & 7) ^ (srow & 7);
  const unsigned short* gp = gsrc + (size_t)srow*DM_ + gch*8;
  char* lp = ldst + tid*16;
#pragma unroll
  for (int j=0;j<4;j++)
    gll16(gp + (size_t)(j*64)*DM_, lp + j*8192);
}
__device__ __forceinline__ void stageB(const unsigned short* __restrict__ gsrc,
                                       char* ldst, int tid){
  const int srow = tid >> 3;
  const int gch  = (tid & 7) ^ (srow & 7);
  const unsigned short* gp = gsrc + (size_t)srow*DM_ + gch*8;
  char* lp = ldst + tid*16;
#pragma unroll
  for (int j=0;j<2;j++)
    gll16(gp + (size_t)(j*64)*DM_, lp + j*8192);
}

template<int MODE>
__global__ __launch_bounds__(512, 2) void k_gemm256(
    const unsigned short* __restrict__ A,
    const unsigned short* __restrict__ w0,
    const unsigned short* __restrict__ w1,
    const unsigned short* __restrict__ w2,
    const float* __restrict__ b0,
    const float* __restrict__ b1,
    const float* __restrict__ b2,
    unsigned short* __restrict__ Qb,
    unsigned short* __restrict__ Kb,
    unsigned short* __restrict__ VTb,
    float* __restrict__ Fout)
{
  extern __shared__ char smem[];
  char* aL = smem;            // 2 x 32KB A tiles (256 rows x 64 cols)
  char* bL = smem + 65536;    // 2 x 16KB B tiles (128 rows x 64 cols)
  const int tid = threadIdx.x, lane = tid & 63, w = tid >> 6;
  const int qc = lane & 15, g = lane >> 4;
  const int wm = (w >> 1)*64, wn = (w & 1)*64;

  int mat, mt, nt;
  {
    int id = blockIdx.x;
    if (MODE == 0){
      int wg = (id & 7)*96 + (id >> 3);     // bijective XCD chunking (768%8==0)
      mat = wg >> 8; int rem = wg & 255;
      mt = (rem >> 3)*256; nt = (rem & 7)*128;
    } else {
      int wg = (id & 7)*32 + (id >> 3);     // 256%8==0
      mat = 0; mt = (wg >> 3)*256; nt = (wg & 7)*128;
    }
  }
  const unsigned short* Wt = (MODE==1)? w0 : ((mat==0)? w0 : (mat==1)? w1 : w2);
  const float* bias        = (MODE==1)? b0 : ((mat==0)? b0 : (mat==1)? b1 : b2);

  const unsigned short* Ab = A  + (size_t)mt*DM_;
  const unsigned short* Bb = Wt + (size_t)nt*DM_;

  // prologue: 2 K-tiles in flight (12 gll16/thread)
  stageA(Ab,      aL,         tid);
  stageB(Bb,      bL,         tid);
  stageA(Ab + 64, aL + 32768, tid);
  stageB(Bb + 64, bL + 16384, tid);

  f32x4 acc[4][4] = {};

  for (int kt = 0; kt < 16; ++kt){
    const int bu = kt & 1;
    if (kt < 15) asm volatile("s_waitcnt vmcnt(6)" ::: "memory");
    else         asm volatile("s_waitcnt vmcnt(0)" ::: "memory");
    __builtin_amdgcn_s_barrier();
    __builtin_amdgcn_sched_barrier(0);
    const char* aT = aL + bu*32768;
    const char* bT = bL + bu*16384;

    bf16x8 bfr[4][2], af[4][2];
#pragma unroll
    for (int n=0;n<4;n++)
#pragma unroll
      for (int ks=0;ks<2;ks++){
        int row = wn + n*16 + qc;
        bfr[n][ks] = *(const bf16x8*)(bT + row*128 + ((ks*64 + g*16) ^ ((row&7)<<4)));
      }
#pragma unroll
    for (int m=0;m<4;m++)
#pragma unroll
      for (int ks=0;ks<2;ks++){
        int row = wm + m*16 + qc;
        af[m][ks] = *(const bf16x8*)(aT + row*128 + ((ks*64 + g*16) ^ ((row&7)<<4)));
      }
    __builtin_amdgcn_s_setprio(1);
#pragma unroll
    for (int m=0;m<2;m++)
#pragma unroll
      for (int n=0;n<4;n++)
#pragma unroll
        for (int ks=0;ks<2;ks++)
          acc[m][n] = __builtin_amdgcn_mfma_f32_16x16x32_bf16(af[m][ks], bfr[n][ks], acc[m][n], 0,0,0);
    __builtin_amdgcn_s_setprio(0);
    asm volatile("s_waitcnt lgkmcnt(0)" ::: "memory");
    __builtin_amdgcn_sched_barrier(0);
    __builtin_amdgcn_s_barrier();
    __builtin_amdgcn_sched_barrier(0);
    if (kt < 14){
      stageA(Ab + (size_t)(kt+2)*64, aL + bu*32768, tid);
      stageB(Bb + (size_t)(kt+2)*64, bL + bu*16384, tid);
    }
    __builtin_amdgcn_s_setprio(1);
#pragma unroll
    for (int m=2;m<4;m++)
#pragma unroll
      for (int n=0;n<4;n++)
#pragma unroll
        for (int ks=0;ks<2;ks++)
          acc[m][n] = __builtin_amdgcn_mfma_f32_16x16x32_bf16(af[m][ks], bfr[n][ks], acc[m][n], 0,0,0);
    __builtin_amdgcn_s_setprio(0);
  }

  if (MODE == 1){
#pragma unroll
    for (int n=0;n<4;n++){
      int col = nt + wn + n*16 + qc;
      float bv = bias[col];
#pragma unroll
      for (int m=0;m<4;m++){
#pragma unroll
        for (int r=0;r<4;r++){
          int mrow = mt + wm + m*16 + g*4 + r;
          Fout[(size_t)mrow*DM_ + col] = acc[m][n][r] + bv;
        }
      }
    }
  } else if (mat < 2){
    // token-major [8192][1024]: adjacent lanes -> adjacent cols (coalesced)
    unsigned short* out = (mat==0)? Qb : Kb;
#pragma unroll
    for (int n=0;n<4;n++){
      int col = nt + wn + n*16 + qc;
      float bv = bias[col];
#pragma unroll
      for (int m=0;m<4;m++){
#pragma unroll
        for (int r=0;r<4;r++){
          int mrow = mt + wm + m*16 + g*4 + r;
          out[(size_t)mrow*DM_ + col] = f2bf(acc[m][n][r] + bv);
        }
      }
    }
  } else {
#pragma unroll
    for (int n=0;n<4;n++){
      int col = nt + wn + n*16 + qc;
      float bv = bias[col];
      int hh = col >> 6, d = col & 63;
#pragma unroll
      for (int m=0;m<4;m++){
        int mrow0 = mt + wm + m*16 + g*4;     // 4 consecutive tokens
        int b = mrow0 >> 11, ntk = mrow0 & (NS_-1);
        int pos = (ntk & ~12) | ((ntk & 4) << 1) | ((ntk & 8) >> 1);  // swap bits 2,3
        ushort4 o;
        o.x = f2bf(acc[m][n][0] + bv);
        o.y = f2bf(acc[m][n][1] + bv);
        o.z = f2bf(acc[m][n][2] + bv);
        o.w = f2bf(acc[m][n][3] + bv);
        *(ushort4*)(VTb + (((size_t)(b*H_ + hh)*HD_ + d)*NS_ + pos)) = o;
      }
    }
  }
}

// ---------------- flat RoPE on token-major Q,K; Q scaled by 0.125*log2(e) ----------------
#define QSCALE 0.18033688011112042f   // 0.125 * log2(e): softmax runs in log2 units
__global__ void k_rope(unsigned short* __restrict__ Qb, unsigned short* __restrict__ Kb,
                       const float2* __restrict__ tab)
{
  const int t = threadIdx.x;
  const long token = (long)blockIdx.x*2 + (t >> 7);
  const int fd = (t & 127)*8;                // flat dim, 8 per thread, same head
  const int n = (int)(token & (NS_-1));
  const int d = fd & 63;
  const float2* tb = tab + n*30;
  float2 cs[8];
#pragma unroll
  for (int j=0;j<8;j++){
    int e = d + j;
    if (e < 60){
      int c = e/20; int rr = e - 20*c; if (rr >= 10) rr -= 10;
      cs[j] = tb[c*10 + rr];                 // per-ELEMENT freq (tile, not interleave)
    } else cs[j] = make_float2(1.f, 0.f);    // pass-through as rotation by 0
  }
  size_t base = (size_t)token*DM_ + fd;
#pragma unroll
  for (int which = 0; which < 2; which++){
    unsigned short* P = which ? Kb : Qb;
    float sc = which ? 1.f : QSCALE;
    ushort4 va = *(ushort4*)(P + base);
    ushort4 vb = *(ushort4*)(P + base + 4);
    float x[8] = {bf2f(va.x),bf2f(va.y),bf2f(va.z),bf2f(va.w),
                  bf2f(vb.x),bf2f(vb.y),bf2f(vb.z),bf2f(vb.w)};
    unsigned short o[8];
#pragma unroll
    for (int j=0;j<8;j+=2){
      o[j]   = f2bf((x[j]*cs[j].x     - x[j+1]*cs[j].y)  *sc);
      o[j+1] = f2bf((x[j+1]*cs[j+1].x + x[j]*cs[j+1].y)  *sc);
    }
    ushort4 oa = {o[0],o[1],o[2],o[3]}, ob = {o[4],o[5],o[6],o[7]};
    *(ushort4*)(P + base)     = oa;
    *(ushort4*)(P + base + 4) = ob;
  }
}

// ---------------- 4-warp flash attention, 32x32 MFMA, swapped QK^T ----------------
// Q,K token-major [8192][1024]. grid (bh=64, qblk=16), 4 blocks/CU.
// QK for BOTH 32-key subtiles hoisted before softmax. Softmax log2-domain,
// defer-max, lane-local P. Single-b128 V reads (sigma-permuted VT).
__global__ __launch_bounds__(256, 4) void k_attn(const unsigned short* __restrict__ Q,
                                                 const unsigned short* __restrict__ K,
                                                 const unsigned short* __restrict__ VT,
                                                 unsigned short* __restrict__ ctxout)
{
  __shared__ __attribute__((aligned(16))) char smem[32768]; // 2 bufs x (8KB K + 8KB VT)
  const int tid  = threadIdx.x;
  const int lane = tid & 63, w = tid >> 6;       // w = 0..3
  const int qcol = lane & 31, h = lane >> 5;
  const int sw   = (lane & 7) << 4;
  const int bh   = blockIdx.x;
  const int b    = bh >> 4, head = bh & 15;
  const int q0   = blockIdx.y*128 + w*32;

  const unsigned short* Qp = Q  + ((size_t)(b*NS_ + q0))*DM_ + head*HD_;
  const unsigned short* Kp = K  + ((size_t)(b*NS_))*DM_ + head*HD_;
  const unsigned short* Vp = VT + (size_t)bh*HD_*NS_;

  const int trow = tid >> 3;                 // 0..31
  const int tc   = (tid & 7) ^ (trow & 7);

  bf16x8 qf[4];
#pragma unroll
  for (int i=0;i<4;i++)
    qf[i] = *(const bf16x8*)(Qp + (size_t)qcol*DM_ + 16*i + 8*h);

  {
    const unsigned short* gk = Kp + (size_t)trow*DM_ + tc*8;
    const unsigned short* gv = Vp + (size_t)trow*NS_ + tc*8;
    gll16(gk,          smem + w*1024);
    gll16(gk + 32*DM_, smem + 4096 + w*1024);
    gll16(gv,          smem + 8192 + w*1024);
    gll16(gv + 32*NS_, smem + 8192 + 4096 + w*1024);
  }

  f32x16 ctx0 = {}, ctx1 = {};
  float mrun = -1e30f, lp = 0.f;

  for (int t = 0; t < NS_/64; ++t){
    const int curo = (t & 1) * 16384;
    __syncthreads();
    if (t + 1 < NS_/64){
      const int kb = (t+1)*64;
      const int nxt = ((t+1) & 1) * 16384;
      const unsigned short* gk = Kp + (size_t)(kb + trow)*DM_ + tc*8;
      const unsigned short* gv = Vp + (size_t)trow*NS_ + kb + tc*8;
      gll16(gk,          smem + nxt + w*1024);
      gll16(gk + 32*DM_, smem + nxt + 4096 + w*1024);
      gll16(gv,          smem + nxt + 8192 + w*1024);
      gll16(gv + 32*NS_, smem + nxt + 8192 + 4096 + w*1024);
    }
    const char* kls = smem + curo;
    const char* vls = smem + curo + 8192;

    // ---- hoisted QK^T for both subtiles ----
    f32x16 st0 = {}, st1 = {};
    __builtin_amdgcn_s_setprio(1);
#pragma unroll
    for (int i=0;i<4;i++){
      bf16x8 kf = *(const bf16x8*)(kls + (((qcol)*128 + 32*i + 16*h) ^ sw));
      st0 = __builtin_amdgcn_mfma_f32_32x32x16_bf16(kf, qf[i], st0, 0,0,0);
    }
#pragma unroll
    for (int i=0;i<4;i++){
      bf16x8 kf = *(const bf16x8*)(kls + ((((32 + qcol)*128) + 32*i + 16*h) ^ sw));
      st1 = __builtin_amdgcn_mfma_f32_32x32x16_bf16(kf, qf[i], st1, 0,0,0);
    }
    __builtin_amdgcn_s_setprio(0);

#pragma unroll
    for (int s = 0; s < 2; ++s){
      f32x16& st = s ? st1 : st0;
      float a0 = fmaxf(fmaxf(st[0],  st[1]),  st[2]);
      float a1 = fmaxf(fmaxf(st[3],  st[4]),  st[5]);
      float a2 = fmaxf(fmaxf(st[6],  st[7]),  st[8]);
      float a3 = fmaxf(fmaxf(st[9],  st[10]), st[11]);
      float a4 = fmaxf(fmaxf(st[12], st[13]), st[14]);
      float tm = fmaxf(fmaxf(fmaxf(a0,a1),a2), fmaxf(fmaxf(a3,a4),st[15]));
      if (!__all(tm - mrun <= 11.5f)){
        float tp = fmaxf(tm, __shfl_xor(tm, 32));
        float mnew = fmaxf(mrun, tp);
        float alpha = exp2a(mrun - mnew);
        lp *= alpha;
#pragma unroll
        for (int r=0;r<16;r++){ ctx0[r]*=alpha; ctx1[r]*=alpha; }
        mrun = mnew;
      }
      unsigned u[8];
      float ps = 0.f;
#pragma unroll
      for (int r=0;r<8;r++){
        float ea = exp2a(st[2*r]   - mrun);
        float eb = exp2a(st[2*r+1] - mrun);
        unsigned uu = cvtpk(ea, eb);
        u[r] = uu;
        union { unsigned q; float f; } lo, hi;
        lo.q = uu << 16; hi.q = uu & 0xFFFF0000u;
        ps += lo.f + hi.f;
      }
      lp += ps;
      bf16x8 pf0 = __builtin_bit_cast(bf16x8, make_uint4(u[0],u[1],u[2],u[3]));
      bf16x8 pf1 = __builtin_bit_cast(bf16x8, make_uint4(u[4],u[5],u[6],u[7]));

      __builtin_amdgcn_s_setprio(1);
#pragma unroll
      for (int kc=0; kc<2; ++kc){
        const bf16x8 pf = kc ? pf1 : pf0;
        bf16x8 vf0 = *(const bf16x8*)(vls + ((qcol)*128      + ((64*s + 32*kc + 16*h) ^ sw)));
        ctx0 = __builtin_amdgcn_mfma_f32_32x32x16_bf16(vf0, pf, ctx0, 0,0,0);
        bf16x8 vf1 = *(const bf16x8*)(vls + ((32 + qcol)*128 + ((64*s + 32*kc + 16*h) ^ sw)));
        ctx1 = __builtin_amdgcn_mfma_f32_32x32x16_bf16(vf1, pf, ctx1, 0,0,0);
      }
      __builtin_amdgcn_s_setprio(0);
    }
  }

  float lsum = lp + __shfl_xor(lp, 32);
  float linv = 1.f / lsum;
  __syncthreads();
  char* reg = smem + w*4096;
#pragma unroll
  for (int rq=0; rq<4; ++rq){
    int db0 = 8*rq + 4*h;
    uint2 v0, v1;
    v0.x = pk2(ctx0[4*rq+0]*linv, ctx0[4*rq+1]*linv);
    v0.y = pk2(ctx0[4*rq+2]*linv, ctx0[4*rq+3]*linv);
    v1.x = pk2(ctx1[4*rq+0]*linv, ctx1[4*rq+1]*linv);
    v1.y = pk2(ctx1[4*rq+2]*linv, ctx1[4*rq+3]*linv);
    *(uint2*)(reg + qcol*128 + db0*2)      = v0;
    *(uint2*)(reg + qcol*128 + (32+db0)*2) = v1;
  }
  __syncthreads();
  unsigned short* outp = ctxout + ((size_t)(b*NS_ + q0))*DM_ + head*HD_;
#pragma unroll
  for (int p=0;p<4;p++){
    int row = p*8 + (lane>>3);
    uint4 v = *(const uint4*)(reg + row*128 + (lane&7)*16);
    *(uint4*)(outp + (size_t)row*DM_ + (lane&7)*8) = v;
  }
}

extern "C" void kernel_launch(void* const* d_in, const int* in_sizes, int n_in,
                              void* d_out, int out_size, void* d_ws, size_t ws_size,
                              hipStream_t stream)
{
  const float* hs = (const float*)d_in[0];
  const float* Wq = (const float*)d_in[1];
  const float* bq = (const float*)d_in[2];
  const float* Wk = (const float*)d_in[3];
  const float* bk = (const float*)d_in[4];
  const float* Wv = (const float*)d_in[5];
  const float* bv = (const float*)d_in[6];
  const float* Wo = (const float*)d_in[7];
  const float* bo = (const float*)d_in[8];

  char* ws = (char*)d_ws;
  size_t off = 0;
  auto alloc = [&](size_t b){ void* p = ws + off; off += (b + 255) & ~(size_t)255; return p; };
  unsigned short* xb  = (unsigned short*)alloc((size_t)MTOT*DM_*2);
  unsigned short* wqt = (unsigned short*)alloc((size_t)DM_*DM_*2);
  unsigned short* wkt = (unsigned short*)alloc((size_t)DM_*DM_*2);
  unsigned short* wvt = (unsigned short*)alloc((size_t)DM_*DM_*2);
  unsigned short* wot = (unsigned short*)alloc((size_t)DM_*DM_*2);
  float2*         tab = (float2*)alloc((size_t)NS_*30*sizeof(float2));
  unsigned short* Qb  = (unsigned short*)alloc((size_t)MTOT*DM_*2);
  unsigned short* Kb  = (unsigned short*)alloc((size_t)MTOT*DM_*2);
  unsigned short* VTb = (unsigned short*)alloc((size_t)MTOT*DM_*2);
  unsigned short* cxb = (unsigned short*)alloc((size_t)MTOT*DM_*2);

  hipFuncSetAttribute((const void*)k_gemm256<0>,
                      hipFuncAttributeMaxDynamicSharedMemorySize, 131072);
  hipFuncSetAttribute((const void*)k_gemm256<1>,
                      hipFuncAttributeMaxDynamicSharedMemorySize, 131072);

  k_prep<<<dim3(9224), dim3(256), 0, stream>>>(hs, xb, Wq, Wk, Wv, Wo,
                                               wqt, wkt, wvt, wot, tab);

  k_gemm256<0><<<dim3(768), dim3(512), 98304, stream>>>(
      xb, wqt, wkt, wvt, bq, bk, bv, Qb, Kb, VTb, (float*)nullptr);

  k_rope<<<dim3(MTOT/2), dim3(256), 0, stream>>>(Qb, Kb, tab);

  k_attn<<<dim3(64, 16), dim3(256), 0, stream>>>(Qb, Kb, VTb, cxb);

  k_gemm256<1><<<dim3(256), dim3(512), 98304, stream>>>(
      cxb, wot, nullptr, nullptr, bo, nullptr, nullptr,
      nullptr, nullptr, nullptr, (float*)d_out);
}

// Round 11
// 219.074 us; speedup vs baseline: 1.3676x; 1.0013x over previous
//
#include <hip/hip_runtime.h>
#include <stdint.h>

#define H_   16
#define NS_  2048
#define B_   4
#define DM_  1024
#define HD_  64
#define MTOT (B_*NS_)   // 8192 tokens

typedef __attribute__((ext_vector_type(8)))  short bf16x8;
typedef __attribute__((ext_vector_type(4)))  float f32x4;
typedef __attribute__((ext_vector_type(16))) float f32x16;

__device__ __forceinline__ unsigned short f2bf(float f){
  union { float f; unsigned u; } v; v.f = f;
  unsigned r = v.u + 0x7FFFu + ((v.u >> 16) & 1u);
  return (unsigned short)(r >> 16);
}
__device__ __forceinline__ float bf2f(unsigned short u){
  union { unsigned u; float f; } v; v.u = ((unsigned)u) << 16;
  return v.f;
}
__device__ __forceinline__ unsigned pk2(float a, float b){
  return (unsigned)f2bf(a) | ((unsigned)f2bf(b) << 16);
}
__device__ __forceinline__ unsigned cvtpk(float a, float b){
  unsigned r;
  asm("v_cvt_pk_bf16_f32 %0, %1, %2" : "=v"(r) : "v"(a), "v"(b));
  return r;
}
__device__ __forceinline__ float exp2a(float x){   // bare v_exp_f32 (2^x)
  float r;
  asm("v_exp_f32 %0, %1" : "=v"(r) : "v"(x));
  return r;
}
__device__ __forceinline__ void gll16(const void* g, void* l){
  __builtin_amdgcn_global_load_lds(
      (const __attribute__((address_space(1))) unsigned int*)g,
      (__attribute__((address_space(3))) unsigned int*)l,
      16, 0, 0);
}

// ---------------- fused prep: cast x, transpose-cast 4 weights, rope table ----------------
__global__ void k_prep(const float* __restrict__ hs, unsigned short* __restrict__ xb,
                       const float* __restrict__ W0, const float* __restrict__ W1,
                       const float* __restrict__ W2, const float* __restrict__ W3,
                       unsigned short* __restrict__ T0, unsigned short* __restrict__ T1,
                       unsigned short* __restrict__ T2, unsigned short* __restrict__ T3,
                       float2* __restrict__ tab)
{
  __shared__ float tile[64][65];
  const int bid = blockIdx.x, t = threadIdx.x;
  if (bid < 8192){
    long i = ((long)bid*256 + t)*4;
    float4 v = *(const float4*)(hs + i);
    ushort4 o; o.x=f2bf(v.x); o.y=f2bf(v.y); o.z=f2bf(v.z); o.w=f2bf(v.w);
    *(ushort4*)(xb + i) = o;
    return;
  }
  if (bid < 9216){
    int id = bid - 8192;
    const int z = id >> 8; id &= 255;
    const float* W = (z==0)? W0 : (z==1)? W1 : (z==2)? W2 : W3;
    unsigned short* Wt = (z==0)? T0 : (z==1)? T1 : (z==2)? T2 : T3;
    int kt = (id >> 4)*64, nt = (id & 15)*64;
    int r = t >> 4, c4 = (t & 15)*4;
#pragma unroll
    for (int i=0;i<4;i++){
      int k = r + i*16;
      float4 v = *(const float4*)(W + (size_t)(kt + k)*DM_ + nt + c4);
      tile[k][c4] = v.x; tile[k][c4+1]=v.y; tile[k][c4+2]=v.z; tile[k][c4+3]=v.w;
    }
    __syncthreads();
#pragma unroll
    for (int i=0;i<4;i++){
      int n = r + i*16;
      ushort4 o;
      o.x = f2bf(tile[c4+0][n]); o.y = f2bf(tile[c4+1][n]);
      o.z = f2bf(tile[c4+2][n]); o.w = f2bf(tile[c4+3][n]);
      *(ushort4*)(Wt + (size_t)(nt + n)*DM_ + kt + c4) = o;
    }
    return;
  }
  {
    int n = (bid - 9216)*256 + t;          // 8 blocks x 256 = 2048
    int f = n >> 8, rem = n & 255, hh = rem >> 4, ww = rem & 15;
    float pos[3]; pos[0]=(float)f; pos[1]=(float)hh; pos[2]=(float)ww;
#pragma unroll
    for (int c=0;c<3;c++)
#pragma unroll
      for (int i=0;i<10;i++){
        float inv = exp2f(-(float)i * 1.3287712379549449f);  // 10000^(-i/10)
        float s, co;
        sincosf(pos[c]*inv, &s, &co);
        tab[n*30 + c*10 + i] = make_float2(co, s);
      }
  }
}

// ---------------- 256x128 BK=64 counted-vmcnt GEMM (T2+T3+T4+T5) ----------------
// 512 threads = 8 waves (4M x 2N), per-wave C 64x64 (acc[4][4]).
// LDS 96KB: A dbuf 2x32KB, B dbuf 2x16KB.  vmcnt(6) steady state.
// MODE 0 (QKV fused): 768 blocks.  Q,K token-major [8192][1024];
//   V -> VT_perm (B,H,64,N), sigma-permuted keys (bits 2<->3).
// MODE 1 (O-proj fp32): 256 blocks.
__device__ __forceinline__ void stageA(const unsigned short* __restrict__ gsrc,
                                       char* ldst, int tid){
  const int srow = tid >> 3;
  const int gch  = (tid & 7) ^ (srow & 7);
  const unsigned short* gp = gsrc + (size_t)srow*DM_ + gch*8;
  char* lp = ldst + tid*16;
#pragma unroll
  for (int j=0;j<4;j++)
    gll16(gp + (size_t)(j*64)*DM_, lp + j*8192);
}
__device__ __forceinline__ void stageB(const unsigned short* __restrict__ gsrc,
                                       char* ldst, int tid){
  const int srow = tid >> 3;
  const int gch  = (tid & 7) ^ (srow & 7);
  const unsigned short* gp = gsrc + (size_t)srow*DM_ + gch*8;
  char* lp = ldst + tid*16;
#pragma unroll
  for (int j=0;j<2;j++)
    gll16(gp + (size_t)(j*64)*DM_, lp + j*8192);
}

template<int MODE>
__global__ __launch_bounds__(512, 2) void k_gemm256(
    const unsigned short* __restrict__ A,
    const unsigned short* __restrict__ w0,
    const unsigned short* __restrict__ w1,
    const unsigned short* __restrict__ w2,
    const float* __restrict__ b0,
    const float* __restrict__ b1,
    const float* __restrict__ b2,
    unsigned short* __restrict__ Qb,
    unsigned short* __restrict__ Kb,
    unsigned short* __restrict__ VTb,
    float* __restrict__ Fout)
{
  extern __shared__ char smem[];
  char* aL = smem;            // 2 x 32KB A tiles (256 rows x 64 cols)
  char* bL = smem + 65536;    // 2 x 16KB B tiles (128 rows x 64 cols)
  const int tid = threadIdx.x, lane = tid & 63, w = tid >> 6;
  const int qc = lane & 15, g = lane >> 4;
  const int wm = (w >> 1)*64, wn = (w & 1)*64;

  int mat, mt, nt;
  {
    int id = blockIdx.x;
    if (MODE == 0){
      int wg = (id & 7)*96 + (id >> 3);     // bijective XCD chunking (768%8==0)
      mat = wg >> 8; int rem = wg & 255;
      mt = (rem >> 3)*256; nt = (rem & 7)*128;
    } else {
      int wg = (id & 7)*32 + (id >> 3);     // 256%8==0
      mat = 0; mt = (wg >> 3)*256; nt = (wg & 7)*128;
    }
  }
  const unsigned short* Wt = (MODE==1)? w0 : ((mat==0)? w0 : (mat==1)? w1 : w2);
  const float* bias        = (MODE==1)? b0 : ((mat==0)? b0 : (mat==1)? b1 : b2);

  const unsigned short* Ab = A  + (size_t)mt*DM_;
  const unsigned short* Bb = Wt + (size_t)nt*DM_;

  // prologue: 2 K-tiles in flight (12 gll16/thread)
  stageA(Ab,      aL,         tid);
  stageB(Bb,      bL,         tid);
  stageA(Ab + 64, aL + 32768, tid);
  stageB(Bb + 64, bL + 16384, tid);

  f32x4 acc[4][4] = {};

  for (int kt = 0; kt < 16; ++kt){
    const int bu = kt & 1;
    if (kt < 15) asm volatile("s_waitcnt vmcnt(6)" ::: "memory");
    else         asm volatile("s_waitcnt vmcnt(0)" ::: "memory");
    __builtin_amdgcn_s_barrier();
    __builtin_amdgcn_sched_barrier(0);
    const char* aT = aL + bu*32768;
    const char* bT = bL + bu*16384;

    bf16x8 bfr[4][2], af[4][2];
#pragma unroll
    for (int n=0;n<4;n++)
#pragma unroll
      for (int ks=0;ks<2;ks++){
        int row = wn + n*16 + qc;
        bfr[n][ks] = *(const bf16x8*)(bT + row*128 + ((ks*64 + g*16) ^ ((row&7)<<4)));
      }
#pragma unroll
    for (int m=0;m<4;m++)
#pragma unroll
      for (int ks=0;ks<2;ks++){
        int row = wm + m*16 + qc;
        af[m][ks] = *(const bf16x8*)(aT + row*128 + ((ks*64 + g*16) ^ ((row&7)<<4)));
      }
    __builtin_amdgcn_s_setprio(1);
#pragma unroll
    for (int m=0;m<2;m++)
#pragma unroll
      for (int n=0;n<4;n++)
#pragma unroll
        for (int ks=0;ks<2;ks++)
          acc[m][n] = __builtin_amdgcn_mfma_f32_16x16x32_bf16(af[m][ks], bfr[n][ks], acc[m][n], 0,0,0);
    __builtin_amdgcn_s_setprio(0);
    asm volatile("s_waitcnt lgkmcnt(0)" ::: "memory");
    __builtin_amdgcn_sched_barrier(0);
    __builtin_amdgcn_s_barrier();
    __builtin_amdgcn_sched_barrier(0);
    if (kt < 14){
      stageA(Ab + (size_t)(kt+2)*64, aL + bu*32768, tid);
      stageB(Bb + (size_t)(kt+2)*64, bL + bu*16384, tid);
    }
    __builtin_amdgcn_s_setprio(1);
#pragma unroll
    for (int m=2;m<4;m++)
#pragma unroll
      for (int n=0;n<4;n++)
#pragma unroll
        for (int ks=0;ks<2;ks++)
          acc[m][n] = __builtin_amdgcn_mfma_f32_16x16x32_bf16(af[m][ks], bfr[n][ks], acc[m][n], 0,0,0);
    __builtin_amdgcn_s_setprio(0);
  }

  if (MODE == 1){
#pragma unroll
    for (int n=0;n<4;n++){
      int col = nt + wn + n*16 + qc;
      float bv = bias[col];
#pragma unroll
      for (int m=0;m<4;m++){
#pragma unroll
        for (int r=0;r<4;r++){
          int mrow = mt + wm + m*16 + g*4 + r;
          Fout[(size_t)mrow*DM_ + col] = acc[m][n][r] + bv;
        }
      }
    }
  } else if (mat < 2){
    // token-major [8192][1024]: adjacent lanes -> adjacent cols (coalesced)
    unsigned short* out = (mat==0)? Qb : Kb;
#pragma unroll
    for (int n=0;n<4;n++){
      int col = nt + wn + n*16 + qc;
      float bv = bias[col];
#pragma unroll
      for (int m=0;m<4;m++){
#pragma unroll
        for (int r=0;r<4;r++){
          int mrow = mt + wm + m*16 + g*4 + r;
          out[(size_t)mrow*DM_ + col] = f2bf(acc[m][n][r] + bv);
        }
      }
    }
  } else {
#pragma unroll
    for (int n=0;n<4;n++){
      int col = nt + wn + n*16 + qc;
      float bv = bias[col];
      int hh = col >> 6, d = col & 63;
#pragma unroll
      for (int m=0;m<4;m++){
        int mrow0 = mt + wm + m*16 + g*4;     // 4 consecutive tokens
        int b = mrow0 >> 11, ntk = mrow0 & (NS_-1);
        int pos = (ntk & ~12) | ((ntk & 4) << 1) | ((ntk & 8) >> 1);  // swap bits 2,3
        ushort4 o;
        o.x = f2bf(acc[m][n][0] + bv);
        o.y = f2bf(acc[m][n][1] + bv);
        o.z = f2bf(acc[m][n][2] + bv);
        o.w = f2bf(acc[m][n][3] + bv);
        *(ushort4*)(VTb + (((size_t)(b*H_ + hh)*HD_ + d)*NS_ + pos)) = o;
      }
    }
  }
}

// ---------------- flat RoPE on token-major Q,K; Q scaled by 0.125*log2(e) ----------------
#define QSCALE 0.18033688011112042f   // 0.125 * log2(e): softmax runs in log2 units
__global__ void k_rope(unsigned short* __restrict__ Qb, unsigned short* __restrict__ Kb,
                       const float2* __restrict__ tab)
{
  const int t = threadIdx.x;
  const long token = (long)blockIdx.x*2 + (t >> 7);
  const int fd = (t & 127)*8;                // flat dim, 8 per thread, same head
  const int n = (int)(token & (NS_-1));
  const int d = fd & 63;
  const float2* tb = tab + n*30;
  float2 cs[8];
#pragma unroll
  for (int j=0;j<8;j++){
    int e = d + j;
    if (e < 60){
      int c = e/20; int rr = e - 20*c; if (rr >= 10) rr -= 10;
      cs[j] = tb[c*10 + rr];                 // per-ELEMENT freq (tile, not interleave)
    } else cs[j] = make_float2(1.f, 0.f);    // pass-through as rotation by 0
  }
  size_t base = (size_t)token*DM_ + fd;
#pragma unroll
  for (int which = 0; which < 2; which++){
    unsigned short* P = which ? Kb : Qb;
    float sc = which ? 1.f : QSCALE;
    ushort4 va = *(ushort4*)(P + base);
    ushort4 vb = *(ushort4*)(P + base + 4);
    float x[8] = {bf2f(va.x),bf2f(va.y),bf2f(va.z),bf2f(va.w),
                  bf2f(vb.x),bf2f(vb.y),bf2f(vb.z),bf2f(vb.w)};
    unsigned short o[8];
#pragma unroll
    for (int j=0;j<8;j+=2){
      o[j]   = f2bf((x[j]*cs[j].x     - x[j+1]*cs[j].y)  *sc);
      o[j+1] = f2bf((x[j+1]*cs[j+1].x + x[j]*cs[j+1].y)  *sc);
    }
    ushort4 oa = {o[0],o[1],o[2],o[3]}, ob = {o[4],o[5],o[6],o[7]};
    *(ushort4*)(P + base)     = oa;
    *(ushort4*)(P + base + 4) = ob;
  }
}

// ---------------- 4-warp flash attention, 32x32 MFMA, swapped QK^T ----------------
// Q,K token-major. grid (bh=64, qblk=16), 4 blocks/CU. QK for both subtiles
// hoisted; softmax log2-domain, defer-max, lane-local P.  Softmax denominator
// accumulated on the MATRIX pipe: l_acc = mfma(ones, P_frag) — every output
// reg = sum over keys of the SAME truncated bf16 P values (ratio-consistent),
// removing the 32-op/subtile VALU unpack-add and the final cross-lane reduce.
__global__ __launch_bounds__(256, 4) void k_attn(const unsigned short* __restrict__ Q,
                                                 const unsigned short* __restrict__ K,
                                                 const unsigned short* __restrict__ VT,
                                                 unsigned short* __restrict__ ctxout)
{
  __shared__ __attribute__((aligned(16))) char smem[32768]; // 2 bufs x (8KB K + 8KB VT)
  const int tid  = threadIdx.x;
  const int lane = tid & 63, w = tid >> 6;       // w = 0..3
  const int qcol = lane & 31, h = lane >> 5;
  const int sw   = (lane & 7) << 4;
  const int bh   = blockIdx.x;
  const int b    = bh >> 4, head = bh & 15;
  const int q0   = blockIdx.y*128 + w*32;

  const unsigned short* Qp = Q  + ((size_t)(b*NS_ + q0))*DM_ + head*HD_;
  const unsigned short* Kp = K  + ((size_t)(b*NS_))*DM_ + head*HD_;
  const unsigned short* Vp = VT + (size_t)bh*HD_*NS_;

  const int trow = tid >> 3;                 // 0..31
  const int tc   = (tid & 7) ^ (trow & 7);

  bf16x8 qf[4];
#pragma unroll
  for (int i=0;i<4;i++)
    qf[i] = *(const bf16x8*)(Qp + (size_t)qcol*DM_ + 16*i + 8*h);

  // all-ones A fragment for the denominator MFMA (bf16 1.0 = 0x3F80)
  bf16x8 ones;
#pragma unroll
  for (int i=0;i<8;i++) ones[i] = (short)0x3F80;

  {
    const unsigned short* gk = Kp + (size_t)trow*DM_ + tc*8;
    const unsigned short* gv = Vp + (size_t)trow*NS_ + tc*8;
    gll16(gk,          smem + w*1024);
    gll16(gk + 32*DM_, smem + 4096 + w*1024);
    gll16(gv,          smem + 8192 + w*1024);
    gll16(gv + 32*NS_, smem + 8192 + 4096 + w*1024);
  }

  f32x16 ctx0 = {}, ctx1 = {}, lacc = {};
  float mrun = -1e30f;

  for (int t = 0; t < NS_/64; ++t){
    const int curo = (t & 1) * 16384;
    __syncthreads();
    if (t + 1 < NS_/64){
      const int kb = (t+1)*64;
      const int nxt = ((t+1) & 1) * 16384;
      const unsigned short* gk = Kp + (size_t)(kb + trow)*DM_ + tc*8;
      const unsigned short* gv = Vp + (size_t)trow*NS_ + kb + tc*8;
      gll16(gk,          smem + nxt + w*1024);
      gll16(gk + 32*DM_, smem + nxt + 4096 + w*1024);
      gll16(gv,          smem + nxt + 8192 + w*1024);
      gll16(gv + 32*NS_, smem + nxt + 8192 + 4096 + w*1024);
    }
    const char* kls = smem + curo;
    const char* vls = smem + curo + 8192;

    // ---- hoisted QK^T for both subtiles ----
    f32x16 st0 = {}, st1 = {};
    __builtin_amdgcn_s_setprio(1);
#pragma unroll
    for (int i=0;i<4;i++){
      bf16x8 kf = *(const bf16x8*)(kls + (((qcol)*128 + 32*i + 16*h) ^ sw));
      st0 = __builtin_amdgcn_mfma_f32_32x32x16_bf16(kf, qf[i], st0, 0,0,0);
    }
#pragma unroll
    for (int i=0;i<4;i++){
      bf16x8 kf = *(const bf16x8*)(kls + ((((32 + qcol)*128) + 32*i + 16*h) ^ sw));
      st1 = __builtin_amdgcn_mfma_f32_32x32x16_bf16(kf, qf[i], st1, 0,0,0);
    }
    __builtin_amdgcn_s_setprio(0);

#pragma unroll
    for (int s = 0; s < 2; ++s){
      f32x16& st = s ? st1 : st0;
      float a0 = fmaxf(fmaxf(st[0],  st[1]),  st[2]);
      float a1 = fmaxf(fmaxf(st[3],  st[4]),  st[5]);
      float a2 = fmaxf(fmaxf(st[6],  st[7]),  st[8]);
      float a3 = fmaxf(fmaxf(st[9],  st[10]), st[11]);
      float a4 = fmaxf(fmaxf(st[12], st[13]), st[14]);
      float tm = fmaxf(fmaxf(fmaxf(a0,a1),a2), fmaxf(fmaxf(a3,a4),st[15]));
      if (!__all(tm - mrun <= 11.5f)){
        float tp = fmaxf(tm, __shfl_xor(tm, 32));
        float mnew = fmaxf(mrun, tp);
        float alpha = exp2a(mrun - mnew);
        lacc[0] *= alpha;                    // only reg 0 of lacc is ever read
#pragma unroll
        for (int r=0;r<16;r++){ ctx0[r]*=alpha; ctx1[r]*=alpha; }
        mrun = mnew;
      }
      unsigned u[8];
#pragma unroll
      for (int r=0;r<8;r++){
        float ea = exp2a(st[2*r]   - mrun);
        float eb = exp2a(st[2*r+1] - mrun);
        u[r] = cvtpk(ea, eb);
      }
      bf16x8 pf0 = __builtin_bit_cast(bf16x8, make_uint4(u[0],u[1],u[2],u[3]));
      bf16x8 pf1 = __builtin_bit_cast(bf16x8, make_uint4(u[4],u[5],u[6],u[7]));

      __builtin_amdgcn_s_setprio(1);
      lacc = __builtin_amdgcn_mfma_f32_32x32x16_bf16(ones, pf0, lacc, 0,0,0);
      lacc = __builtin_amdgcn_mfma_f32_32x32x16_bf16(ones, pf1, lacc, 0,0,0);
#pragma unroll
      for (int kc=0; kc<2; ++kc){
        const bf16x8 pf = kc ? pf1 : pf0;
        bf16x8 vf0 = *(const bf16x8*)(vls + ((qcol)*128      + ((64*s + 32*kc + 16*h) ^ sw)));
        ctx0 = __builtin_amdgcn_mfma_f32_32x32x16_bf16(vf0, pf, ctx0, 0,0,0);
        bf16x8 vf1 = *(const bf16x8*)(vls + ((32 + qcol)*128 + ((64*s + 32*kc + 16*h) ^ sw)));
        ctx1 = __builtin_amdgcn_mfma_f32_32x32x16_bf16(vf1, pf, ctx1, 0,0,0);
      }
      __builtin_amdgcn_s_setprio(0);
    }
  }

  float linv = 1.f / lacc[0];               // every reg/lane-half holds the same l
  __syncthreads();
  char* reg = smem + w*4096;
#pragma unroll
  for (int rq=0; rq<4; ++rq){
    int db0 = 8*rq + 4*h;
    uint2 v0, v1;
    v0.x = pk2(ctx0[4*rq+0]*linv, ctx0[4*rq+1]*linv);
    v0.y = pk2(ctx0[4*rq+2]*linv, ctx0[4*rq+3]*linv);
    v1.x = pk2(ctx1[4*rq+0]*linv, ctx1[4*rq+1]*linv);
    v1.y = pk2(ctx1[4*rq+2]*linv, ctx1[4*rq+3]*linv);
    *(uint2*)(reg + qcol*128 + db0*2)      = v0;
    *(uint2*)(reg + qcol*128 + (32+db0)*2) = v1;
  }
  __syncthreads();
  unsigned short* outp = ctxout + ((size_t)(b*NS_ + q0))*DM_ + head*HD_;
#pragma unroll
  for (int p=0;p<4;p++){
    int row = p*8 + (lane>>3);
    uint4 v = *(const uint4*)(reg + row*128 + (lane&7)*16);
    *(uint4*)(outp + (size_t)row*DM_ + (lane&7)*8) = v;
  }
}

extern "C" void kernel_launch(void* const* d_in, const int* in_sizes, int n_in,
                              void* d_out, int out_size, void* d_ws, size_t ws_size,
                              hipStream_t stream)
{
  const float* hs = (const float*)d_in[0];
  const float* Wq = (const float*)d_in[1];
  const float* bq = (const float*)d_in[2];
  const float* Wk = (const float*)d_in[3];
  const float* bk = (const float*)d_in[4];
  const float* Wv = (const float*)d_in[5];
  const float* bv = (const float*)d_in[6];
  const float* Wo = (const float*)d_in[7];
  const float* bo = (const float*)d_in[8];

  char* ws = (char*)d_ws;
  size_t off = 0;
  auto alloc = [&](size_t b){ void* p = ws + off; off += (b + 255) & ~(size_t)255; return p; };
  unsigned short* xb  = (unsigned short*)alloc((size_t)MTOT*DM_*2);
  unsigned short* wqt = (unsigned short*)alloc((size_t)DM_*DM_*2);
  unsigned short* wkt = (unsigned short*)alloc((size_t)DM_*DM_*2);
  unsigned short* wvt = (unsigned short*)alloc((size_t)DM_*DM_*2);
  unsigned short* wot = (unsigned short*)alloc((size_t)DM_*DM_*2);
  float2*         tab = (float2*)alloc((size_t)NS_*30*sizeof(float2));
  unsigned short* Qb  = (unsigned short*)alloc((size_t)MTOT*DM_*2);
  unsigned short* Kb  = (unsigned short*)alloc((size_t)MTOT*DM_*2);
  unsigned short* VTb = (unsigned short*)alloc((size_t)MTOT*DM_*2);
  unsigned short* cxb = (unsigned short*)alloc((size_t)MTOT*DM_*2);

  hipFuncSetAttribute((const void*)k_gemm256<0>,
                      hipFuncAttributeMaxDynamicSharedMemorySize, 131072);
  hipFuncSetAttribute((const void*)k_gemm256<1>,
                      hipFuncAttributeMaxDynamicSharedMemorySize, 131072);

  k_prep<<<dim3(9224), dim3(256), 0, stream>>>(hs, xb, Wq, Wk, Wv, Wo,
                                               wqt, wkt, wvt, wot, tab);

  k_gemm256<0><<<dim3(768), dim3(512), 98304, stream>>>(
      xb, wqt, wkt, wvt, bq, bk, bv, Qb, Kb, VTb, (float*)nullptr);

  k_rope<<<dim3(MTOT/2), dim3(256), 0, stream>>>(Qb, Kb, tab);

  k_attn<<<dim3(64, 16), dim3(256), 0, stream>>>(Qb, Kb, VTb, cxb);

  k_gemm256<1><<<dim3(256), dim3(512), 98304, stream>>>(
      cxb, wot, nullptr, nullptr, bo, nullptr, nullptr,
      nullptr, nullptr, nullptr, (float*)d_out);
}